// Round 15
// baseline (8866.979 us; speedup 1.0000x reference)
//
#include <hip/hip_runtime.h>
#include <cstddef>
#include <cstdint>

// ---------------------------------------------------------------------------
// HOPE block forward. bf16 activations + bf16-MFMA GEMMs (global_load_lds,
// XOR-swizzled LDS, counted-vmcnt pipeline, BK=32 high-occupancy cores,
// XCD-chunked swizzles, fused rowsums, algebraic target-GEMM elimination).
// B=8, N=8192, DIM=384, HID=1536, 4 chunks, rows/chunk = 16384.
// ---------------------------------------------------------------------------

typedef __bf16 bf16;
typedef __bf16 bf16x4 __attribute__((ext_vector_type(4)));
typedef __bf16 bf16x8 __attribute__((ext_vector_type(8)));
typedef float  f32x4  __attribute__((ext_vector_type(4)));

constexpr float INV_CNT = 1.0f / 6291456.0f;   // 1/(16384*384)

__device__ __forceinline__ float fast_gelu(float x) {
  float u = 0.7978845608028654f * (x + 0.044715f * x * x * x);
  return x / (1.0f + __expf(-2.0f * u));
}
__device__ __forceinline__ float fast_gelu_grad(float x) {
  float x2 = x * x;
  float u = 0.7978845608028654f * (x + 0.044715f * x * x2);
  float s = 1.0f / (1.0f + __expf(-2.0f * u));
  return s + x * s * (1.0f - s) * 1.5957691216057308f * (1.0f + 0.134145f * x2);
}
__device__ __forceinline__ f32x4 gelu4(f32x4 v) {
  v[0] = fast_gelu(v[0]); v[1] = fast_gelu(v[1]);
  v[2] = fast_gelu(v[2]); v[3] = fast_gelu(v[3]);
  return v;
}
__device__ __forceinline__ bf16x4 tobf4(f32x4 v) {
  bf16x4 o; o[0] = (bf16)v[0]; o[1] = (bf16)v[1]; o[2] = (bf16)v[2]; o[3] = (bf16)v[3];
  return o;
}
__device__ __forceinline__ f32x4 tof4(bf16x4 v) {
  return f32x4{(float)v[0], (float)v[1], (float)v[2], (float)v[3]};
}

__device__ __forceinline__ void gload16(const bf16* g, void* lds) {
  __builtin_amdgcn_global_load_lds(
      (const __attribute__((address_space(1))) void*)g,
      (__attribute__((address_space(3))) void*)lds, 16, 0, 0);
}

// counted vmcnt wait (T4)
template <int N>
__device__ __forceinline__ void wait_vmcnt() {
  if constexpr (N == 0)      asm volatile("s_waitcnt vmcnt(0)" ::: "memory");
  else if constexpr (N == 2) asm volatile("s_waitcnt vmcnt(2)" ::: "memory");
  else if constexpr (N == 3) asm volatile("s_waitcnt vmcnt(3)" ::: "memory");
  else if constexpr (N == 4) asm volatile("s_waitcnt vmcnt(4)" ::: "memory");
  __builtin_amdgcn_sched_barrier(0);
}

// bijective XCD-chunked remap (m204)
__device__ __forceinline__ int xcd_chunk(int id, int n) {
  int q = n >> 3, r = n & 7;
  int xcd = id & 7, pos = id >> 3;
  return (xcd < r ? xcd * (q + 1) : r * (q + 1) + (xcd - r) * q) + pos;
}

// ---- LayerNorm --------------------------------------------------------------
__global__ __launch_bounds__(64)
void ln_kernel(const float* __restrict__ x, const float* __restrict__ g,
               const float* __restrict__ b, bf16* __restrict__ y,
               int shift, int base, int stride) {
  int r = blockIdx.x;
  int src = ((r >> shift) * stride) + base + (r & ((1 << shift) - 1));
  int lane = threadIdx.x;
  const float* xr = x + (size_t)src * 384;
  float vals[6];
  float s = 0.f, s2 = 0.f;
#pragma unroll
  for (int i = 0; i < 6; ++i) {
    float v = xr[lane + i * 64];
    vals[i] = v; s += v; s2 += v * v;
  }
#pragma unroll
  for (int o = 32; o > 0; o >>= 1) { s += __shfl_xor(s, o); s2 += __shfl_xor(s2, o); }
  float m = s * (1.0f / 384.0f);
  float var = s2 * (1.0f / 384.0f) - m * m;
  float rr = rsqrtf(var + 1e-5f);
  bf16* yr = y + (size_t)r * 384;
#pragma unroll
  for (int i = 0; i < 6; ++i) {
    int c = lane + i * 64;
    yr[c] = (bf16)((vals[i] - m) * rr * g[c] + b[c]);
  }
}

// ---- weight transpose core --------------------------------------------------
__device__ __forceinline__ void trw_body(const float* in, bf16* out, int R, int C,
                                         int c0, int r0, int tid) {
  __shared__ float t[32][33];
  int tr = tid >> 3, tc = (tid & 7) * 4;
  f32x4 v = *(const f32x4*)&in[(size_t)(r0 + tr) * C + c0 + tc];
  t[tr][tc + 0] = v[0]; t[tr][tc + 1] = v[1]; t[tr][tc + 2] = v[2]; t[tr][tc + 3] = v[3];
  __syncthreads();
  bf16x4 o;
  o[0] = (bf16)t[tc + 0][tr]; o[1] = (bf16)t[tc + 1][tr];
  o[2] = (bf16)t[tc + 2][tr]; o[3] = (bf16)t[tc + 3][tr];
  *(bf16x4*)&out[(size_t)(c0 + tr) * R + r0 + tc] = o;
}

__global__ __launch_bounds__(256)
void trans_state(const float* __restrict__ SW1, const float* __restrict__ SW2,
                 bf16* __restrict__ sw1t, bf16* __restrict__ sw2t) {
  int z = blockIdx.z;
  if (z < 5)
    trw_body(SW1 + (size_t)z * 589824, sw1t + (size_t)z * 589824, 384, 1536,
             blockIdx.x * 32, blockIdx.y * 32, threadIdx.x);
  else
    trw_body(SW2 + (size_t)(z - 5) * 589824, sw2t + (size_t)(z - 5) * 589824, 1536, 384,
             blockIdx.y * 32, blockIdx.x * 32, threadIdx.x);
}

__global__ __launch_bounds__(256)
void trans_static(const float* __restrict__ qW, const float* __restrict__ outW,
                  const float* __restrict__ cW1, const float* __restrict__ cW2,
                  bf16* __restrict__ qwt, bf16* __restrict__ owt,
                  bf16* __restrict__ cw1t, bf16* __restrict__ cw2t) {
  int z = blockIdx.z;
  if (z < 2) {
    if (blockIdx.x >= 12) return;
    trw_body(z ? outW : qW, z ? owt : qwt, 384, 384,
             blockIdx.x * 32, blockIdx.y * 32, threadIdx.x);
  } else if (z < 5) {
    int lc = z - 2;
    trw_body(cW1 + (size_t)lc * 589824, cw1t + (size_t)lc * 589824, 384, 1536,
             blockIdx.x * 32, blockIdx.y * 32, threadIdx.x);
  } else {
    int lc = z - 5;
    trw_body(cW2 + (size_t)lc * 589824, cw2t + (size_t)lc * 589824, 1536, 384,
             blockIdx.y * 32, blockIdx.x * 32, threadIdx.x);
  }
}

// ---- transpose bf16 [R][C] -> [C][R] (Kb -> Kbt) ---------------------------
__global__ __launch_bounds__(256)
void tr_bf(const bf16* __restrict__ in, bf16* __restrict__ out, int R, int C) {
  __shared__ bf16 t[32][36];
  int r0 = blockIdx.x * 32, c0 = blockIdx.y * 32;
  int tr = threadIdx.x >> 3, tc = (threadIdx.x & 7) * 4;
  bf16x4 v = *(const bf16x4*)&in[(size_t)(r0 + tr) * C + c0 + tc];
  t[tr][tc + 0] = v[0]; t[tr][tc + 1] = v[1]; t[tr][tc + 2] = v[2]; t[tr][tc + 3] = v[3];
  __syncthreads();
  bf16x4 o;
  o[0] = t[tc + 0][tr]; o[1] = t[tc + 1][tr]; o[2] = t[tc + 2][tr]; o[3] = t[tc + 3][tr];
  *(bf16x4*)&out[(size_t)(c0 + tr) * R + r0 + tc] = o;
}

__global__ __launch_bounds__(256)
void copy_bf16(const float* __restrict__ in, bf16* __restrict__ out, int n) {
  int i = (blockIdx.x * 256 + threadIdx.x) * 4;
  if (i < n) {
    f32x4 v = *(const f32x4*)&in[i];
    *(bf16x4*)&out[i] = tobf4(v);
  }
}

// ---- MFMA GEMM: D[i][m] = sum_k W[i][k] * Act[m][k], fused epilogues -------
// BK=32, 64B LDS rows, unit swizzle u^=((row>>1)&3).
enum { E_BF16 = 0, E_GELU, E_PAIR, E_PAIRD, E_SUB, E_SCL, E_MUL, E_F32ADD, E_KV, E_RED2 };

template <int EPI, int BM>
__global__ __launch_bounds__(BM == 128 ? 512 : 256)
void mm_fwd(const bf16* __restrict__ Act, int lda, const bf16* __restrict__ W,
            const float* __restrict__ bias, const bf16* __restrict__ baux,
            const float* __restrict__ faux, float* __restrict__ red,
            bf16* __restrict__ Cb, bf16* __restrict__ C2, bf16* __restrict__ Ct,
            float* __restrict__ Cf, int K, int ldc, int ldt, float scale,
            int croff, int cshift, int cbase, int cstride,
            long zA, long zW, int zB) {
  constexpr int NW = (BM == 128) ? 8 : 4;
  constexpr int NFM = 2;
  constexpr int TW = 8 / NW;
  constexpr int TA = (BM / 16) / NW;
  constexpr int LPT = TW + TA;
  constexpr int SWE = 128 * 32;
  constexpr int SAE = BM * 32;
  constexpr int BUFE = 2 * (SWE + SAE);
  constexpr int SLABE = NW * 16 * 68 * 2;
  constexpr int SMEME = (BUFE > SLABE) ? BUFE : SLABE;
  constexpr bool TRANS = (EPI == E_PAIR || EPI == E_PAIRD || EPI == E_SUB ||
                          EPI == E_SCL || EPI == E_MUL);
  __shared__ bf16 smem[SMEME];
  const int z = blockIdx.z;
  Act += (size_t)z * zA;
  W   += (size_t)z * zW;
  if (bias) bias += (size_t)z * zB;
  const int nx = gridDim.x;
  const int nid = xcd_chunk(blockIdx.y * nx + blockIdx.x, nx * gridDim.y);
  const int m0 = (nid / nx) * BM, i0 = (nid % nx) * 128;
  const int tid = threadIdx.x;
  const int l = tid & 63, w = tid >> 6;
  const int a = l & 15, g = l >> 4;
  const int wi0 = (w & 1) * 64, wm0 = (w >> 1) * 32;
  const int srow = l >> 2;
  const int sue = ((l & 3) ^ ((l >> 3) & 3)) * 8;
  const int fru = (g ^ ((a >> 1) & 3)) << 4;

  const bf16* wp = W   + (size_t)(i0 + srow) * K   + sue;
  const bf16* ap = Act + (size_t)(m0 + srow) * lda + sue;

  f32x4 acc[4][NFM];
#pragma unroll
  for (int i = 0; i < 4; ++i)
#pragma unroll
    for (int j = 0; j < NFM; ++j) acc[i][j] = f32x4{0.f, 0.f, 0.f, 0.f};

  auto stage = [&](int buf, int k0) {
    bf16* dW = smem + buf * SWE;
    bf16* dA = smem + 2 * SWE + buf * SAE;
#pragma unroll
    for (int t = 0; t < TW; ++t) {
      const int seg = w * TW + t;
      gload16(wp + (size_t)(seg * 16) * K + k0, (char*)dW + seg * 1024);
    }
#pragma unroll
    for (int t = 0; t < TA; ++t) {
      const int seg = w * TA + t;
      gload16(ap + (size_t)(seg * 16) * lda + k0, (char*)dA + seg * 1024);
    }
  };

  const int nIt = K >> 5;
  stage(0, 0);
  for (int it = 0; it < nIt; ++it) {
    const int cur = it & 1;
    if (it + 1 < nIt) { stage(cur ^ 1, (it + 1) << 5); wait_vmcnt<LPT>(); }
    else              { wait_vmcnt<0>(); }
    __builtin_amdgcn_s_barrier();
    const bf16* bW = smem + cur * SWE;
    const bf16* bA = smem + 2 * SWE + cur * SAE;
    {
      bf16x8 Af[4], Bf[NFM];
#pragma unroll
      for (int f = 0; f < 4; ++f) {
        const int rW = wi0 + f * 16 + a;
        Af[f] = *(const bf16x8*)((const char*)bW + rW * 64 + fru);
      }
#pragma unroll
      for (int f = 0; f < NFM; ++f) {
        const int rA = wm0 + f * 16 + a;
        Bf[f] = *(const bf16x8*)((const char*)bA + rA * 64 + fru);
      }
#pragma unroll
      for (int fi = 0; fi < 4; ++fi)
#pragma unroll
        for (int fm = 0; fm < NFM; ++fm)
          acc[fi][fm] = __builtin_amdgcn_mfma_f32_16x16x32_bf16(Af[fi], Bf[fm], acc[fi][fm], 0, 0, 0);
    }
    asm volatile("s_waitcnt lgkmcnt(0)" ::: "memory");
    __builtin_amdgcn_s_barrier();
  }

  if constexpr (EPI == E_RED2) {
    float ssum = 0.f;
#pragma unroll
    for (int fi = 0; fi < 4; ++fi) {
      f32x4 b4 = *(const f32x4*)&bias[i0 + wi0 + fi * 16 + g * 4];
#pragma unroll
      for (int fm = 0; fm < NFM; ++fm)
#pragma unroll
        for (int r = 0; r < 4; ++r) {
          float vv = acc[fi][fm][r] + b4[r];
          if (z == 0) ssum += fmaxf(vv, 0.f) + log1pf(__expf(-fabsf(vv)));
          else        ssum += 1.0f / (1.0f + __expf(-vv));
        }
    }
#pragma unroll
    for (int o = 32; o > 0; o >>= 1) ssum += __shfl_xor(ssum, o);
    float* wred = (float*)smem;
    if (l == 0) wred[w] = ssum;
    __syncthreads();
    if (tid == 0) {
      float t2 = 0.f;
      for (int q = 0; q < NW; ++q) t2 += wred[q];
      atomicAdd(&red[z], t2);
    }
    return;
  } else {
    float* T = (float*)smem + w * (16 * 68);
    const int iB = i0 + wi0;
    f32x4 b4 = f32x4{0.f, 0.f, 0.f, 0.f};
    if (bias) b4 = *(const f32x4*)&bias[iB + a * 4];
#pragma unroll
    for (int fm = 0; fm < NFM; ++fm) {
#pragma unroll
      for (int fi = 0; fi < 4; ++fi)
        *(f32x4*)&T[a * 68 + fi * 16 + g * 4] = acc[fi][fm];
      asm volatile("s_waitcnt lgkmcnt(0)" ::: "memory");
      __builtin_amdgcn_sched_barrier(0);

      // ---- row-major pass: coalesced aux reads, all ops here --------------
#pragma unroll
      for (int q = 0; q < 4; ++q) {
        const int ml = wm0 + fm * 16 + q * 4 + g;
        const int trow = q * 4 + g;
        f32x4 v = *(const f32x4*)&T[trow * 68 + a * 4];
        v += b4;
        if constexpr (EPI == E_F32ADD) {
          const int rr = croff + m0 + ml;
          const int crow = ((rr >> cshift) * cstride) + cbase + (rr & ((1 << cshift) - 1));
          const size_t cb = (size_t)crow * ldc + iB + a * 4;
          v += *(const f32x4*)&faux[cb];
          *(f32x4*)&Cf[cb] = v;
        } else {
          const size_t cb = (size_t)(m0 + ml) * ldc + iB + a * 4;
          if constexpr (EPI == E_BF16) {
            *(bf16x4*)&Cb[cb] = tobf4(v);
          } else if constexpr (EPI == E_KV) {
            bf16* DST = (z == 0) ? Cb : C2;
            *(bf16x4*)&DST[cb] = tobf4(v);
          } else if constexpr (EPI == E_GELU) {
            *(bf16x4*)&Cb[cb] = tobf4(gelu4(v));
          } else if constexpr (EPI == E_PAIR) {
            // Cb = gelu'(h1), C2 = gelu(h1), slab <- gelu(h1)
            f32x4 gp;
            gp[0] = fast_gelu_grad(v[0]); gp[1] = fast_gelu_grad(v[1]);
            gp[2] = fast_gelu_grad(v[2]); gp[3] = fast_gelu_grad(v[3]);
            f32x4 gv = gelu4(v);
            *(bf16x4*)&Cb[cb] = tobf4(gp);
            *(bf16x4*)&C2[cb] = tobf4(gv);
            *(f32x4*)&T[trow * 68 + a * 4] = gv;
          } else if constexpr (EPI == E_PAIRD) {
            // Cb = gelu'(h1), C2 = gelu(h1) - aux (diff), slab <- gelu(h1)
            f32x4 gp;
            gp[0] = fast_gelu_grad(v[0]); gp[1] = fast_gelu_grad(v[1]);
            gp[2] = fast_gelu_grad(v[2]); gp[3] = fast_gelu_grad(v[3]);
            f32x4 gv = gelu4(v);
            f32x4 d = gv - tof4(*(const bf16x4*)&baux[cb]);
            *(bf16x4*)&Cb[cb] = tobf4(gp);
            *(bf16x4*)&C2[cb] = tobf4(d);
            *(f32x4*)&T[trow * 68 + a * 4] = gv;
          } else if constexpr (EPI == E_SUB) {
            f32x4 t4 = tof4(*(const bf16x4*)&baux[cb]);
            v = (v - t4) * scale;
            *(bf16x4*)&Cb[cb] = tobf4(v);
            *(f32x4*)&T[trow * 68 + a * 4] = v;
          } else if constexpr (EPI == E_SCL) {
            v = v * scale;
            *(bf16x4*)&Cb[cb] = tobf4(v);
            *(f32x4*)&T[trow * 68 + a * 4] = v;
          } else if constexpr (EPI == E_MUL) {
            f32x4 h4 = tof4(*(const bf16x4*)&baux[cb]);   // gelu'(h1) bf16
            v *= h4;
            *(f32x4*)&T[trow * 68 + a * 4] = v;
          }
        }
      }

      // ---- transposed pass: pure LDS column read -> coalesced store -------
      if constexpr (TRANS) {
        asm volatile("s_waitcnt lgkmcnt(0)" ::: "memory");
        __builtin_amdgcn_sched_barrier(0);
        const int mg = m0 + wm0 + fm * 16;
        bf16x8 o0, o1;
#pragma unroll
        for (int j = 0; j < 16; ++j) {
          float vv = T[j * 68 + l];
          if (j < 8) o0[j] = (bf16)vv; else o1[j - 8] = (bf16)vv;
        }
        *(bf16x8*)&Ct[(size_t)(iB + l) * ldt + mg] = o0;
        *(bf16x8*)&Ct[(size_t)(iB + l) * ldt + mg + 8] = o1;
      }
    }
  }
}

// ---- combined TN GEMMs, L2-grouped, BK=32, with fused Q-row sums -----------
__global__ __launch_bounds__(512)
void mm_tn2c(const bf16* __restrict__ P1, int ldP1, const bf16* __restrict__ Q1, int ldQ1,
             float* __restrict__ Ga, int ldGa,
             const bf16* __restrict__ P2, int ldP2, const bf16* __restrict__ Q2, int ldQ2,
             float* __restrict__ Gb, int ldGb, int mlen,
             float* __restrict__ G4s, float* __restrict__ G2s) {
  constexpr int SBE = 128 * 32;
  __shared__ bf16 smem[4 * SBE];       // 32 KB -> 4 blocks/CU
  const int nid = xcd_chunk(blockIdx.x, gridDim.x);
  const int grp = nid / 36, pair = nid % 36;
  const int part = grp & 1, zsl = grp >> 1;
  const bf16* P; const bf16* Q; float* G; float* Gsum;
  int ldP, ldQ, ldG, p0, q0;
  if (part == 0) {
    P = P1; Q = Q1; G = Ga; ldP = ldP1; ldQ = ldQ1; ldG = ldGa; Gsum = G4s;
    p0 = (pair / 3) * 128; q0 = (pair % 3) * 128;
  } else {
    P = P2; Q = Q2; G = Gb; ldP = ldP2; ldQ = ldQ2; ldG = ldGb; Gsum = G2s;
    p0 = (pair / 12) * 128; q0 = (pair % 12) * 128;
  }
  const bool doSum = (p0 == 0);
  const int tid = threadIdx.x;
  const int mb = zsl * mlen;
  const int l = tid & 63, w = tid >> 6;
  const int a = l & 15, g = l >> 4;
  const int wp0 = (w & 1) * 64, wq0 = (w >> 1) * 32;
  const int sue = ((l & 3) ^ ((l >> 3) & 3)) * 8;
  const int fru = (g ^ ((a >> 1) & 3)) << 4;

  const bf16* pP = P + (size_t)(p0 + w * 16 + (l >> 2)) * ldP + sue;
  const bf16* pQ = Q + (size_t)(q0 + w * 16 + (l >> 2)) * ldQ + sue;

  f32x4 acc[4][2];
#pragma unroll
  for (int i = 0; i < 4; ++i)
#pragma unroll
    for (int j = 0; j < 2; ++j) acc[i][j] = f32x4{0.f, 0.f, 0.f, 0.f};
  float qsum = 0.f;
  const int sumoff = (w * 16 + (l >> 2)) * 64 + (l & 3) * 16;  // byte in Q buf

  auto stage = [&](int buf, int m0) {
    bf16* dP = smem + buf * SBE;
    bf16* dQ = smem + 2 * SBE + buf * SBE;
    gload16(pP + m0, (char*)dP + w * 1024);
    gload16(pQ + m0, (char*)dQ + w * 1024);
  };

  const int nIt = mlen >> 5;
  stage(0, mb);
  for (int it = 0; it < nIt; ++it) {
    const int cur = it & 1;
    if (it + 1 < nIt) { stage(cur ^ 1, mb + ((it + 1) << 5)); wait_vmcnt<2>(); }
    else              { wait_vmcnt<0>(); }
    __builtin_amdgcn_s_barrier();
    const bf16* bP = smem + cur * SBE;
    const bf16* bQ = smem + 2 * SBE + cur * SBE;
    {
      bf16x8 Pf[4], Qf[2];
#pragma unroll
      for (int f = 0; f < 4; ++f) {
        const int rP = wp0 + f * 16 + a;
        Pf[f] = *(const bf16x8*)((const char*)bP + rP * 64 + fru);
      }
#pragma unroll
      for (int f = 0; f < 2; ++f) {
        const int rQ = wq0 + f * 16 + a;
        Qf[f] = *(const bf16x8*)((const char*)bQ + rQ * 64 + fru);
      }
#pragma unroll
      for (int f1 = 0; f1 < 4; ++f1)
#pragma unroll
        for (int f2 = 0; f2 < 2; ++f2)
          acc[f1][f2] = __builtin_amdgcn_mfma_f32_16x16x32_bf16(Pf[f1], Qf[f2], acc[f1][f2], 0, 0, 0);
    }
    if (doSum) {   // full-row sums are invariant to the in-row unit swizzle
      bf16x8 s0 = *(const bf16x8*)((const char*)bQ + sumoff);
#pragma unroll
      for (int e = 0; e < 8; ++e) qsum += (float)s0[e];
    }
    asm volatile("s_waitcnt lgkmcnt(0)" ::: "memory");
    __builtin_amdgcn_s_barrier();
  }
#pragma unroll
  for (int f1 = 0; f1 < 4; ++f1)
#pragma unroll
    for (int f2 = 0; f2 < 2; ++f2)
#pragma unroll
      for (int r = 0; r < 4; ++r)
        atomicAdd(&G[(size_t)(p0 + wp0 + f1 * 16 + g * 4 + r) * ldG + q0 + wq0 + f2 * 16 + a],
                  acc[f1][f2][r]);
  if (doSum) {
    qsum += __shfl_xor(qsum, 1);
    qsum += __shfl_xor(qsum, 2);
    if ((l & 3) == 0) atomicAdd(&Gsum[q0 + w * 16 + (l >> 2)], qsum);
  }
}

// ---- RoPE in place ---------------------------------------------------------
__global__ __launch_bounds__(256)
void rope_kernel(bf16* __restrict__ qb, int rbase) {
  int idx = blockIdx.x * blockDim.x + threadIdx.x;
  int row = idx >> 4, hd = idx & 15;
  int j = (rbase + row) & 2047;
  float pos[3] = { (float)(j >> 8), (float)((j >> 4) & 15), (float)(j & 15) };
  const float freqs[4] = { 1.0f, 0.1f, 0.01f, 0.001f };
  bf16* p = qb + (size_t)row * 384 + hd * 24;
#pragma unroll
  for (int s = 0; s < 3; ++s) {
    bf16x8 vv = *(bf16x8*)(p + s * 8);
#pragma unroll
    for (int pr = 0; pr < 4; ++pr) {
      float ang = pos[s] * freqs[pr];
      float si, co;
      sincosf(ang, &si, &co);
      float e0 = (float)vv[2 * pr], e1 = (float)vv[2 * pr + 1];
      vv[2 * pr]     = (bf16)(e0 * co - e1 * si);
      vv[2 * pr + 1] = (bf16)(e0 * si + e1 * co);
    }
    *(bf16x8*)(p + s * 8) = vv;
  }
}

// ---- combined sumsq over G1..G4, per memory i (grid (516,5)) ---------------
__global__ __launch_bounds__(256)
void sumsq_all(const float* __restrict__ G1, const float* __restrict__ G2,
               const float* __restrict__ G3, const float* __restrict__ G4,
               float* __restrict__ red) {
  int i = blockIdx.y, bx = blockIdx.x;
  const float* base; int per, lb, nb;
  if (bx < 256)      { base = G1 + (size_t)i * 589824; per = 589824; lb = bx;       nb = 256; }
  else if (bx < 512) { base = G3 + (size_t)i * 589824; per = 589824; lb = bx - 256; nb = 256; }
  else if (bx < 514) { base = G2 + (size_t)i * 1536;   per = 1536;   lb = bx - 512; nb = 2; }
  else               { base = G4 + (size_t)i * 384;    per = 384;    lb = bx - 514; nb = 2; }
  float s = 0.f;
  for (int idx = lb * 256 + threadIdx.x; idx < per; idx += nb * 256) {
    float v = base[idx]; s += v * v;
  }
  __shared__ float sm[256];
  sm[threadIdx.x] = s; __syncthreads();
  for (int o = 128; o > 0; o >>= 1) {
    if (threadIdx.x < o) sm[threadIdx.x] += sm[threadIdx.x + o];
    __syncthreads();
  }
  if (threadIdx.x == 0) atomicAdd(&red[2 + i], sm[0]);
}

// ---- combined state update (grid (1032,5)) ---------------------------------
__global__ __launch_bounds__(256)
void update_all(float* __restrict__ SW1, float* __restrict__ SB1,
                float* __restrict__ SW2, float* __restrict__ SB2,
                const float* __restrict__ G1, const float* __restrict__ G2,
                const float* __restrict__ G3, const float* __restrict__ G4,
                const float* __restrict__ red) {
  int i = blockIdx.y, bx = blockIdx.x;
  float* S; const float* G; int per, lb, nb;
  if (bx < 512)       { S = SW1; G = G1; per = 589824; lb = bx;        nb = 512; }
  else if (bx < 1024) { S = SW2; G = G3; per = 589824; lb = bx - 512;  nb = 512; }
  else if (bx < 1028) { S = SB1; G = G2; per = 1536;   lb = bx - 1024; nb = 4; }
  else                { S = SB2; G = G4; per = 384;    lb = bx - 1028; nb = 4; }
  size_t base = (size_t)i * per;
  float em = 0.01f * red[0] * INV_CNT;
  float am = red[1] * INV_CNT;
  float norm = sqrtf(red[2 + i]);
  float sc = fminf(1.0f, 1.0f / (norm + 1e-12f));
  float ws_ = 1.0f - am;
  float gs = em * sc;
  for (int idx = lb * 256 + (int)threadIdx.x; idx < per; idx += nb * 256)
    S[base + idx] = ws_ * S[base + idx] - gs * G[base + idx];
}

// ---------------------------------------------------------------------------
extern "C" void kernel_launch(void* const* d_in, const int* in_sizes, int n_in,
                              void* d_out, int out_size, void* d_ws, size_t ws_size,
                              hipStream_t stream) {
  const float* x    = (const float*)d_in[0];
  const float* n1g  = (const float*)d_in[1];
  const float* n1b  = (const float*)d_in[2];
  const float* qW   = (const float*)d_in[3];
  const float* tW1  = (const float*)d_in[4];
  const float* tb1  = (const float*)d_in[5];
  const float* tW2  = (const float*)d_in[6];
  const float* tb2  = (const float*)d_in[7];
  const float* outW = (const float*)d_in[8];
  const float* outb = (const float*)d_in[9];
  const float* n2g  = (const float*)d_in[10];
  const float* n2b  = (const float*)d_in[11];
  const float* cW1  = (const float*)d_in[12];
  const float* cb1  = (const float*)d_in[13];
  const float* cW2  = (const float*)d_in[14];
  const float* cb2  = (const float*)d_in[15];
  float* out = (float*)d_out;

  const size_t W1SZ = 384 * 1536, W2SZ = 1536 * 384;
  const size_t STATE = 5 * W1SZ + 5 * 1536 + 5 * W2SZ + 5 * 384;
  const size_t BF_W = 21 * W1SZ + 2 * 147456;
  const size_t CHUNK_BF = 4 * (size_t)16384 * 384;                 // Yc,Kb,Vb,Kbt
  const size_t FIXEDF = 2 * STATE + 16 + BF_W / 2 + CHUNK_BF / 2;
  size_t MS = 16384;
  while (MS > 2048 && (FIXEDF + MS * 3840) * 4 > ws_size) MS >>= 1;
  if ((FIXEDF + MS * 3840) * 4 > ws_size) {
    hipMemcpyAsync(d_out, d_in[0], (size_t)25165824 * 4, hipMemcpyDeviceToDevice, stream);
    return;
  }
  const int NS = (int)(16384 / MS);
  const int iMS = (int)MS;

  float* ws = (float*)d_ws;
  size_t off = 0;
  auto alloc = [&](size_t n) { float* p = ws + off; off += n; return p; };
  auto balloc = [&](size_t n) { bf16* p = (bf16*)(ws + off); off += (n + 1) / 2; return p; };
  float* SW1 = alloc(5 * W1SZ);
  float* SB1 = alloc(5 * 1536);
  float* SW2 = alloc(5 * W2SZ);
  float* SB2 = alloc(5 * 384);
  float* G1  = alloc(5 * W1SZ);
  float* G2  = alloc(5 * 1536);
  float* G3  = alloc(5 * W2SZ);
  float* G4  = alloc(5 * 384);
  float* RED = alloc(16);
  bf16* Yc   = balloc((size_t)16384 * 384);
  bf16* Kb   = balloc((size_t)16384 * 384);
  bf16* Vb   = balloc((size_t)16384 * 384);
  bf16* Kbt  = balloc((size_t)16384 * 384);
  bf16* sw1t = balloc(5 * W1SZ);
  bf16* sw2t = balloc(5 * W2SZ);
  bf16* sw2c = balloc(5 * W2SZ);
  bf16* qwt  = balloc(147456);
  bf16* owt  = balloc(147456);
  bf16* cw1t = balloc(3 * W1SZ);
  bf16* cw2t = balloc(3 * W2SZ);
  bf16* pool = balloc(MS * 3072);
  bf16* GH1t = balloc(MS * 1536);
  bf16* DAt  = balloc(MS * 1536);
  bf16* OD   = balloc(MS * 384);
  bf16* ODt  = balloc(MS * 384);
  bf16* T2   = balloc(MS * 384);
  bf16* Tt   = balloc(MS * 384);
  bf16* H1r  = pool;                 // gelu'(h1) [m][1536]
  bf16* GH1k = pool + MS * 1536;     // gelu(h1) rm / GHv

  hipMemcpyAsync(SW1, tW1, 5 * W1SZ * 4, hipMemcpyDeviceToDevice, stream);
  hipMemcpyAsync(SB1, tb1, 5 * 1536 * 4, hipMemcpyDeviceToDevice, stream);
  hipMemcpyAsync(SW2, tW2, 5 * W2SZ * 4, hipMemcpyDeviceToDevice, stream);
  hipMemcpyAsync(SB2, tb2, 5 * 384 * 4, hipMemcpyDeviceToDevice, stream);

  trans_static<<<dim3(48, 12, 8), 256, 0, stream>>>(qW, outW, cW1, cW2, qwt, owt, cw1t, cw2t);

  const size_t grads_bytes = STATE * 4;
  const int gm  = iMS / 128;
  const int gm2 = iMS / 64;
  int mlen_t = iMS / 8; if (mlen_t < 128) mlen_t = 128;
  if (mlen_t > 2048) mlen_t = 2048;
  const int nzt = iMS / mlen_t;
  const int tn_grid = 36 * 2 * nzt;
  const float SC = 2.0f * INV_CNT;
  const size_t MSR = (size_t)iMS * 384;

  for (int c = 0; c < 4; ++c) {
    hipMemsetAsync(G1, 0, grads_bytes, stream);
    hipMemsetAsync(RED, 0, 64, stream);
    trans_state<<<dim3(48, 12, 10), 256, 0, stream>>>(SW1, SW2, sw1t, sw2t);
    copy_bf16<<<dim3(2880), 256, 0, stream>>>(SW2, sw2c, (int)(5 * W2SZ));

    ln_kernel<<<dim3(16384), dim3(64), 0, stream>>>(x, n1g, n1b, Yc, 11, c * 2048, 8192);

    // ---- gen (pair-fused fwd1 + z-batched fwd2) ----
    for (int s = 0; s < NS; ++s) {
      const bf16* Ys = Yc + (size_t)s * MSR;
      mm_fwd<E_GELU, 128><<<dim3(24, gm), 512, 0, stream>>>(Ys, 384, sw1t,
          SB1, nullptr, nullptr, nullptr, pool, nullptr, nullptr, nullptr,
          384, 3072, 0, 0.f, 0, 30, 0, 0, 0, 0, 0);
      mm_fwd<E_KV, 64><<<dim3(3, gm2, 2), 256, 0, stream>>>(pool, 3072, sw2t,
          SB2, nullptr, nullptr, nullptr, Kb + s * MSR, Vb + s * MSR, nullptr, nullptr,
          1536, 384, 0, 0.f, 0, 30, 0, 0, 1536, (long)W2SZ, 384);
      mm_fwd<E_GELU, 128><<<dim3(24, gm), 512, 0, stream>>>(Ys, 384, sw1t + 2 * W1SZ,
          SB1 + 2 * 1536, nullptr, nullptr, nullptr, pool, nullptr, nullptr, nullptr,
          384, 3072, 0, 0.f, 0, 30, 0, 0, 0, 0, 0);
      mm_fwd<E_RED2, 64><<<dim3(3, gm2, 2), 256, 0, stream>>>(pool, 3072, sw2t + 2 * W2SZ,
          SB2 + 2 * 384, nullptr, nullptr, RED, nullptr, nullptr, nullptr, nullptr,
          1536, 384, 0, 0.f, 0, 30, 0, 0, 1536, (long)W2SZ, 384);
    }

    // ---- q/out per slice ----
    for (int s = 0; s < NS; ++s) {
      const bf16* Ys = Yc + (size_t)s * MSR;
      mm_fwd<E_BF16, 64><<<dim3(3, gm2), 256, 0, stream>>>(Ys, 384, qwt,
          nullptr, nullptr, nullptr, nullptr, Tt, nullptr, nullptr, nullptr,
          384, 384, 0, 0.f, 0, 30, 0, 0, 0, 0, 0);
      rope_kernel<<<dim3(iMS / 16), 256, 0, stream>>>(Tt, s * iMS);
      mm_fwd<E_GELU, 128><<<dim3(12, gm), 512, 0, stream>>>(Tt, 384, sw1t + 4 * W1SZ,
          SB1 + 4 * 1536, nullptr, nullptr, nullptr, GH1k, nullptr, nullptr, nullptr,
          384, 1536, 0, 0.f, 0, 30, 0, 0, 0, 0, 0);
      mm_fwd<E_BF16, 64><<<dim3(3, gm2), 256, 0, stream>>>(GH1k, 1536, sw2t + 4 * W2SZ,
          SB2 + 4 * 384, nullptr, nullptr, nullptr, T2, nullptr, nullptr, nullptr,
          1536, 384, 0, 0.f, 0, 30, 0, 0, 0, 0, 0);
      mm_fwd<E_F32ADD, 64><<<dim3(3, gm2), 256, 0, stream>>>(T2, 384, owt, outb,
          nullptr, x, nullptr, nullptr, nullptr, nullptr, out,
          384, 384, 0, 0.f, s * iMS, 11, c * 2048, 8192, 0, 0, 0);
    }

    rope_kernel<<<dim3(1024), 256, 0, stream>>>(Kb, 0);
    tr_bf<<<dim3(512, 12), 256, 0, stream>>>(Kb, Kbt, 16384, 384);

    // ---- per-slice, per-memory grads ----
    for (int s = 0; s < NS; ++s) {
      const bf16* Ks = Kb + (size_t)s * MSR;
      const bf16* Vs = Vb + (size_t)s * MSR;
      for (int i = 0; i < 5; ++i) {
        if (i < 4) {
          // GHv = gelu(v@W1+b1)
          mm_fwd<E_GELU, 128><<<dim3(12, gm), 512, 0, stream>>>(Vs, 384, sw1t + i * W1SZ,
              SB1 + i * 1536, nullptr, nullptr, nullptr, GH1k, nullptr, nullptr, nullptr,
              384, 1536, 0, 0.f, 0, 30, 0, 0, 0, 0, 0);
          // k-fwd1: gelu'(h1k)->H1r, D=gelu(h1k)-GHv -> DAt(rm), GH1t
          mm_fwd<E_PAIRD, 128><<<dim3(12, gm), 512, 0, stream>>>(Ks, 384, sw1t + i * W1SZ,
              SB1 + i * 1536, GH1k, nullptr, nullptr, H1r, DAt, GH1t, nullptr,
              384, 1536, iMS, 0.f, 0, 30, 0, 0, 0, 0, 0);
          // od = D @ W2^T * sc (biases cancel)
          mm_fwd<E_SCL, 64><<<dim3(3, gm2), 256, 0, stream>>>(DAt, 1536, sw2t + i * W2SZ,
              nullptr, nullptr, nullptr, nullptr, OD, nullptr, ODt, nullptr,
              1536, 384, iMS, SC, 0, 30, 0, 0, 0, 0, 0);
        } else {
          mm_fwd<E_PAIR, 128><<<dim3(12, gm), 512, 0, stream>>>(Ks, 384, sw1t + 4 * W1SZ,
              SB1 + 4 * 1536, nullptr, nullptr, nullptr, H1r, GH1k, GH1t, nullptr,
              384, 1536, iMS, 0.f, 0, 30, 0, 0, 0, 0, 0);
          mm_fwd<E_SUB, 64><<<dim3(3, gm2), 256, 0, stream>>>(GH1k, 1536, sw2t + 4 * W2SZ,
              SB2 + 4 * 384, Vs, nullptr, nullptr, OD, nullptr, ODt, nullptr,
              1536, 384, iMS, SC, 0, 30, 0, 0, 0, 0, 0);
        }
        mm_fwd<E_MUL, 128><<<dim3(12, gm), 512, 0, stream>>>(OD, 384, sw2c + i * W2SZ,
            nullptr, H1r, nullptr, nullptr, nullptr, nullptr, DAt, nullptr,
            384, 1536, iMS, 0.f, 0, 30, 0, 0, 0, 0, 0);
        mm_tn2c<<<dim3(tn_grid), 512, 0, stream>>>(
            GH1t, iMS, ODt, iMS, G3 + i * W2SZ, 384,
            Kbt + (size_t)s * iMS, 16384, DAt, iMS, G1 + i * W1SZ, 1536, mlen_t,
            G4 + i * 384, G2 + i * 1536);
      }
    }

    sumsq_all<<<dim3(516, 5), 256, 0, stream>>>(G1, G2, G3, G4, RED);
    update_all<<<dim3(1032, 5), 256, 0, stream>>>(SW1, SB1, SW2, SB2, G1, G2, G3, G4, RED);
  }

  // ---- norm2 + 3 CMS MLP layers (+ fused final residual) ----
  const int NCS = (int)(65536 / MS);
  for (int s2 = 0; s2 < NCS; ++s2) {
    float* outp = out + (size_t)s2 * MSR;
    ln_kernel<<<dim3(iMS), dim3(64), 0, stream>>>(out, n2g, n2b, OD, 30, s2 * iMS, 0);
    bf16* hc = OD; bf16* hn = T2;
    for (int lc = 0; lc < 3; ++lc) {
      mm_fwd<E_GELU, 128><<<dim3(12, gm), 512, 0, stream>>>(hc, 384, cw1t + lc * W1SZ,
          cb1 + lc * 1536, nullptr, nullptr, nullptr, GH1k, nullptr, nullptr, nullptr,
          384, 1536, 0, 0.f, 0, 30, 0, 0, 0, 0, 0);
      if (lc < 2) {
        mm_fwd<E_BF16, 64><<<dim3(3, gm2), 256, 0, stream>>>(GH1k, 1536, cw2t + lc * W2SZ,
            cb2 + lc * 384, nullptr, nullptr, nullptr, hn, nullptr, nullptr, nullptr,
            1536, 384, 0, 0.f, 0, 30, 0, 0, 0, 0, 0);
        bf16* t = hc; hc = hn; hn = t;
      } else {
        mm_fwd<E_F32ADD, 64><<<dim3(3, gm2), 256, 0, stream>>>(GH1k, 1536, cw2t + lc * W2SZ,
            cb2 + lc * 384, nullptr, outp, nullptr, nullptr, nullptr, nullptr, outp,
            1536, 384, 0, 0.f, 0, 30, 0, 0, 0, 0, 0);
      }
    }
  }
}

// Round 16
// 8813.690 us; speedup vs baseline: 1.0060x; 1.0060x over previous
//
#include <hip/hip_runtime.h>
#include <cstddef>
#include <cstdint>

// ---------------------------------------------------------------------------
// HOPE block forward. bf16 activations + bf16-MFMA GEMMs (global_load_lds,
// XOR-swizzled LDS, counted-vmcnt pipeline, BK=32 high-occupancy cores,
// XCD-chunked swizzles, fused rowsums, algebraic target-GEMM elimination,
// shared-exp fused gelu+gelu' epilogues).
// B=8, N=8192, DIM=384, HID=1536, 4 chunks, rows/chunk = 16384.
// ---------------------------------------------------------------------------

typedef __bf16 bf16;
typedef __bf16 bf16x4 __attribute__((ext_vector_type(4)));
typedef __bf16 bf16x8 __attribute__((ext_vector_type(8)));
typedef float  f32x4  __attribute__((ext_vector_type(4)));

constexpr float INV_CNT = 1.0f / 6291456.0f;   // 1/(16384*384)

__device__ __forceinline__ float fast_gelu(float x) {
  float u = 0.7978845608028654f * (x + 0.044715f * x * x * x);
  return x / (1.0f + __expf(-2.0f * u));
}
__device__ __forceinline__ f32x4 gelu4(f32x4 v) {
  v[0] = fast_gelu(v[0]); v[1] = fast_gelu(v[1]);
  v[2] = fast_gelu(v[2]); v[3] = fast_gelu(v[3]);
  return v;
}
// fused gelu + gelu' with a single shared exp per element
__device__ __forceinline__ void gelu_both4(f32x4 v, f32x4& g, f32x4& gp) {
#pragma unroll
  for (int e = 0; e < 4; ++e) {
    float x = v[e];
    float x2 = x * x;
    float u = 0.7978845608028654f * (x + 0.044715f * x * x2);
    float s = 1.0f / (1.0f + __expf(-2.0f * u));
    g[e]  = x * s;
    gp[e] = s + x * s * (1.0f - s) * 1.5957691216057308f * (1.0f + 0.134145f * x2);
  }
}
__device__ __forceinline__ bf16x4 tobf4(f32x4 v) {
  bf16x4 o; o[0] = (bf16)v[0]; o[1] = (bf16)v[1]; o[2] = (bf16)v[2]; o[3] = (bf16)v[3];
  return o;
}
__device__ __forceinline__ f32x4 tof4(bf16x4 v) {
  return f32x4{(float)v[0], (float)v[1], (float)v[2], (float)v[3]};
}

__device__ __forceinline__ void gload16(const bf16* g, void* lds) {
  __builtin_amdgcn_global_load_lds(
      (const __attribute__((address_space(1))) void*)g,
      (__attribute__((address_space(3))) void*)lds, 16, 0, 0);
}

// counted vmcnt wait (T4)
template <int N>
__device__ __forceinline__ void wait_vmcnt() {
  if constexpr (N == 0)      asm volatile("s_waitcnt vmcnt(0)" ::: "memory");
  else if constexpr (N == 2) asm volatile("s_waitcnt vmcnt(2)" ::: "memory");
  else if constexpr (N == 3) asm volatile("s_waitcnt vmcnt(3)" ::: "memory");
  else if constexpr (N == 4) asm volatile("s_waitcnt vmcnt(4)" ::: "memory");
  __builtin_amdgcn_sched_barrier(0);
}

// bijective XCD-chunked remap (m204)
__device__ __forceinline__ int xcd_chunk(int id, int n) {
  int q = n >> 3, r = n & 7;
  int xcd = id & 7, pos = id >> 3;
  return (xcd < r ? xcd * (q + 1) : r * (q + 1) + (xcd - r) * q) + pos;
}

// ---- LayerNorm --------------------------------------------------------------
__global__ __launch_bounds__(64)
void ln_kernel(const float* __restrict__ x, const float* __restrict__ g,
               const float* __restrict__ b, bf16* __restrict__ y,
               int shift, int base, int stride) {
  int r = blockIdx.x;
  int src = ((r >> shift) * stride) + base + (r & ((1 << shift) - 1));
  int lane = threadIdx.x;
  const float* xr = x + (size_t)src * 384;
  float vals[6];
  float s = 0.f, s2 = 0.f;
#pragma unroll
  for (int i = 0; i < 6; ++i) {
    float v = xr[lane + i * 64];
    vals[i] = v; s += v; s2 += v * v;
  }
#pragma unroll
  for (int o = 32; o > 0; o >>= 1) { s += __shfl_xor(s, o); s2 += __shfl_xor(s2, o); }
  float m = s * (1.0f / 384.0f);
  float var = s2 * (1.0f / 384.0f) - m * m;
  float rr = rsqrtf(var + 1e-5f);
  bf16* yr = y + (size_t)r * 384;
#pragma unroll
  for (int i = 0; i < 6; ++i) {
    int c = lane + i * 64;
    yr[c] = (bf16)((vals[i] - m) * rr * g[c] + b[c]);
  }
}

// ---- weight transpose core --------------------------------------------------
__device__ __forceinline__ void trw_body(const float* in, bf16* out, int R, int C,
                                         int c0, int r0, int tid) {
  __shared__ float t[32][33];
  int tr = tid >> 3, tc = (tid & 7) * 4;
  f32x4 v = *(const f32x4*)&in[(size_t)(r0 + tr) * C + c0 + tc];
  t[tr][tc + 0] = v[0]; t[tr][tc + 1] = v[1]; t[tr][tc + 2] = v[2]; t[tr][tc + 3] = v[3];
  __syncthreads();
  bf16x4 o;
  o[0] = (bf16)t[tc + 0][tr]; o[1] = (bf16)t[tc + 1][tr];
  o[2] = (bf16)t[tc + 2][tr]; o[3] = (bf16)t[tc + 3][tr];
  *(bf16x4*)&out[(size_t)(c0 + tr) * R + r0 + tc] = o;
}

__global__ __launch_bounds__(256)
void trans_state(const float* __restrict__ SW1, const float* __restrict__ SW2,
                 bf16* __restrict__ sw1t, bf16* __restrict__ sw2t) {
  int z = blockIdx.z;
  if (z < 5)
    trw_body(SW1 + (size_t)z * 589824, sw1t + (size_t)z * 589824, 384, 1536,
             blockIdx.x * 32, blockIdx.y * 32, threadIdx.x);
  else
    trw_body(SW2 + (size_t)(z - 5) * 589824, sw2t + (size_t)(z - 5) * 589824, 1536, 384,
             blockIdx.y * 32, blockIdx.x * 32, threadIdx.x);
}

__global__ __launch_bounds__(256)
void trans_static(const float* __restrict__ qW, const float* __restrict__ outW,
                  const float* __restrict__ cW1, const float* __restrict__ cW2,
                  bf16* __restrict__ qwt, bf16* __restrict__ owt,
                  bf16* __restrict__ cw1t, bf16* __restrict__ cw2t) {
  int z = blockIdx.z;
  if (z < 2) {
    if (blockIdx.x >= 12) return;
    trw_body(z ? outW : qW, z ? owt : qwt, 384, 384,
             blockIdx.x * 32, blockIdx.y * 32, threadIdx.x);
  } else if (z < 5) {
    int lc = z - 2;
    trw_body(cW1 + (size_t)lc * 589824, cw1t + (size_t)lc * 589824, 384, 1536,
             blockIdx.x * 32, blockIdx.y * 32, threadIdx.x);
  } else {
    int lc = z - 5;
    trw_body(cW2 + (size_t)lc * 589824, cw2t + (size_t)lc * 589824, 1536, 384,
             blockIdx.y * 32, blockIdx.x * 32, threadIdx.x);
  }
}

// ---- transpose bf16 [R][C] -> [C][R] (Kb -> Kbt) ---------------------------
__global__ __launch_bounds__(256)
void tr_bf(const bf16* __restrict__ in, bf16* __restrict__ out, int R, int C) {
  __shared__ bf16 t[32][36];
  int r0 = blockIdx.x * 32, c0 = blockIdx.y * 32;
  int tr = threadIdx.x >> 3, tc = (threadIdx.x & 7) * 4;
  bf16x4 v = *(const bf16x4*)&in[(size_t)(r0 + tr) * C + c0 + tc];
  t[tr][tc + 0] = v[0]; t[tr][tc + 1] = v[1]; t[tr][tc + 2] = v[2]; t[tr][tc + 3] = v[3];
  __syncthreads();
  bf16x4 o;
  o[0] = t[tc + 0][tr]; o[1] = t[tc + 1][tr]; o[2] = t[tc + 2][tr]; o[3] = t[tc + 3][tr];
  *(bf16x4*)&out[(size_t)(c0 + tr) * R + r0 + tc] = o;
}

__global__ __launch_bounds__(256)
void copy_bf16(const float* __restrict__ in, bf16* __restrict__ out, int n) {
  int i = (blockIdx.x * 256 + threadIdx.x) * 4;
  if (i < n) {
    f32x4 v = *(const f32x4*)&in[i];
    *(bf16x4*)&out[i] = tobf4(v);
  }
}

// ---- MFMA GEMM: D[i][m] = sum_k W[i][k] * Act[m][k], fused epilogues -------
// BK=32, 64B LDS rows, unit swizzle u^=((row>>1)&3).
enum { E_BF16 = 0, E_GELU, E_PAIR, E_PAIRD, E_SUB, E_SCL, E_MUL, E_F32ADD, E_KV, E_RED2 };

template <int EPI, int BM>
__global__ __launch_bounds__(BM == 128 ? 512 : 256)
void mm_fwd(const bf16* __restrict__ Act, int lda, const bf16* __restrict__ W,
            const float* __restrict__ bias, const bf16* __restrict__ baux,
            const float* __restrict__ faux, float* __restrict__ red,
            bf16* __restrict__ Cb, bf16* __restrict__ C2, bf16* __restrict__ Ct,
            float* __restrict__ Cf, int K, int ldc, int ldt, float scale,
            int croff, int cshift, int cbase, int cstride,
            long zA, long zW, int zB) {
  constexpr int NW = (BM == 128) ? 8 : 4;
  constexpr int NFM = 2;
  constexpr int TW = 8 / NW;
  constexpr int TA = (BM / 16) / NW;
  constexpr int LPT = TW + TA;
  constexpr int SWE = 128 * 32;
  constexpr int SAE = BM * 32;
  constexpr int BUFE = 2 * (SWE + SAE);
  constexpr int SLABE = NW * 16 * 68 * 2;
  constexpr int SMEME = (BUFE > SLABE) ? BUFE : SLABE;
  constexpr bool TRANS = (EPI == E_PAIR || EPI == E_PAIRD || EPI == E_SUB ||
                          EPI == E_SCL || EPI == E_MUL);
  __shared__ bf16 smem[SMEME];
  const int z = blockIdx.z;
  Act += (size_t)z * zA;
  W   += (size_t)z * zW;
  if (bias) bias += (size_t)z * zB;
  const int nx = gridDim.x;
  const int nid = xcd_chunk(blockIdx.y * nx + blockIdx.x, nx * gridDim.y);
  const int m0 = (nid / nx) * BM, i0 = (nid % nx) * 128;
  const int tid = threadIdx.x;
  const int l = tid & 63, w = tid >> 6;
  const int a = l & 15, g = l >> 4;
  const int wi0 = (w & 1) * 64, wm0 = (w >> 1) * 32;
  const int srow = l >> 2;
  const int sue = ((l & 3) ^ ((l >> 3) & 3)) * 8;
  const int fru = (g ^ ((a >> 1) & 3)) << 4;

  const bf16* wp = W   + (size_t)(i0 + srow) * K   + sue;
  const bf16* ap = Act + (size_t)(m0 + srow) * lda + sue;

  f32x4 acc[4][NFM];
#pragma unroll
  for (int i = 0; i < 4; ++i)
#pragma unroll
    for (int j = 0; j < NFM; ++j) acc[i][j] = f32x4{0.f, 0.f, 0.f, 0.f};

  auto stage = [&](int buf, int k0) {
    bf16* dW = smem + buf * SWE;
    bf16* dA = smem + 2 * SWE + buf * SAE;
#pragma unroll
    for (int t = 0; t < TW; ++t) {
      const int seg = w * TW + t;
      gload16(wp + (size_t)(seg * 16) * K + k0, (char*)dW + seg * 1024);
    }
#pragma unroll
    for (int t = 0; t < TA; ++t) {
      const int seg = w * TA + t;
      gload16(ap + (size_t)(seg * 16) * lda + k0, (char*)dA + seg * 1024);
    }
  };

  const int nIt = K >> 5;
  stage(0, 0);
  for (int it = 0; it < nIt; ++it) {
    const int cur = it & 1;
    if (it + 1 < nIt) { stage(cur ^ 1, (it + 1) << 5); wait_vmcnt<LPT>(); }
    else              { wait_vmcnt<0>(); }
    __builtin_amdgcn_s_barrier();
    const bf16* bW = smem + cur * SWE;
    const bf16* bA = smem + 2 * SWE + cur * SAE;
    {
      bf16x8 Af[4], Bf[NFM];
#pragma unroll
      for (int f = 0; f < 4; ++f) {
        const int rW = wi0 + f * 16 + a;
        Af[f] = *(const bf16x8*)((const char*)bW + rW * 64 + fru);
      }
#pragma unroll
      for (int f = 0; f < NFM; ++f) {
        const int rA = wm0 + f * 16 + a;
        Bf[f] = *(const bf16x8*)((const char*)bA + rA * 64 + fru);
      }
#pragma unroll
      for (int fi = 0; fi < 4; ++fi)
#pragma unroll
        for (int fm = 0; fm < NFM; ++fm)
          acc[fi][fm] = __builtin_amdgcn_mfma_f32_16x16x32_bf16(Af[fi], Bf[fm], acc[fi][fm], 0, 0, 0);
    }
    asm volatile("s_waitcnt lgkmcnt(0)" ::: "memory");
    __builtin_amdgcn_s_barrier();
  }

  if constexpr (EPI == E_RED2) {
    float ssum = 0.f;
#pragma unroll
    for (int fi = 0; fi < 4; ++fi) {
      f32x4 b4 = *(const f32x4*)&bias[i0 + wi0 + fi * 16 + g * 4];
#pragma unroll
      for (int fm = 0; fm < NFM; ++fm)
#pragma unroll
        for (int r = 0; r < 4; ++r) {
          float vv = acc[fi][fm][r] + b4[r];
          if (z == 0) ssum += fmaxf(vv, 0.f) + log1pf(__expf(-fabsf(vv)));
          else        ssum += 1.0f / (1.0f + __expf(-vv));
        }
    }
#pragma unroll
    for (int o = 32; o > 0; o >>= 1) ssum += __shfl_xor(ssum, o);
    float* wred = (float*)smem;
    if (l == 0) wred[w] = ssum;
    __syncthreads();
    if (tid == 0) {
      float t2 = 0.f;
      for (int q = 0; q < NW; ++q) t2 += wred[q];
      atomicAdd(&red[z], t2);
    }
    return;
  } else {
    float* T = (float*)smem + w * (16 * 68);
    const int iB = i0 + wi0;
    f32x4 b4 = f32x4{0.f, 0.f, 0.f, 0.f};
    if (bias) b4 = *(const f32x4*)&bias[iB + a * 4];
#pragma unroll
    for (int fm = 0; fm < NFM; ++fm) {
#pragma unroll
      for (int fi = 0; fi < 4; ++fi)
        *(f32x4*)&T[a * 68 + fi * 16 + g * 4] = acc[fi][fm];
      asm volatile("s_waitcnt lgkmcnt(0)" ::: "memory");
      __builtin_amdgcn_sched_barrier(0);

      // ---- row-major pass: coalesced aux reads, all ops here --------------
#pragma unroll
      for (int q = 0; q < 4; ++q) {
        const int ml = wm0 + fm * 16 + q * 4 + g;
        const int trow = q * 4 + g;
        f32x4 v = *(const f32x4*)&T[trow * 68 + a * 4];
        v += b4;
        if constexpr (EPI == E_F32ADD) {
          const int rr = croff + m0 + ml;
          const int crow = ((rr >> cshift) * cstride) + cbase + (rr & ((1 << cshift) - 1));
          const size_t cb = (size_t)crow * ldc + iB + a * 4;
          v += *(const f32x4*)&faux[cb];
          *(f32x4*)&Cf[cb] = v;
        } else {
          const size_t cb = (size_t)(m0 + ml) * ldc + iB + a * 4;
          if constexpr (EPI == E_BF16) {
            *(bf16x4*)&Cb[cb] = tobf4(v);
          } else if constexpr (EPI == E_KV) {
            bf16* DST = (z == 0) ? Cb : C2;
            *(bf16x4*)&DST[cb] = tobf4(v);
          } else if constexpr (EPI == E_GELU) {
            *(bf16x4*)&Cb[cb] = tobf4(gelu4(v));
          } else if constexpr (EPI == E_PAIR) {
            // Cb = gelu'(h1), C2 = gelu(h1), slab <- gelu(h1)  [shared exp]
            f32x4 gv, gp;
            gelu_both4(v, gv, gp);
            *(bf16x4*)&Cb[cb] = tobf4(gp);
            *(bf16x4*)&C2[cb] = tobf4(gv);
            *(f32x4*)&T[trow * 68 + a * 4] = gv;
          } else if constexpr (EPI == E_PAIRD) {
            // Cb = gelu'(h1), C2 = gelu(h1) - aux, slab <- gelu(h1) [shared exp]
            f32x4 gv, gp;
            gelu_both4(v, gv, gp);
            f32x4 d = gv - tof4(*(const bf16x4*)&baux[cb]);
            *(bf16x4*)&Cb[cb] = tobf4(gp);
            *(bf16x4*)&C2[cb] = tobf4(d);
            *(f32x4*)&T[trow * 68 + a * 4] = gv;
          } else if constexpr (EPI == E_SUB) {
            f32x4 t4 = tof4(*(const bf16x4*)&baux[cb]);
            v = (v - t4) * scale;
            *(bf16x4*)&Cb[cb] = tobf4(v);
            *(f32x4*)&T[trow * 68 + a * 4] = v;
          } else if constexpr (EPI == E_SCL) {
            v = v * scale;
            *(bf16x4*)&Cb[cb] = tobf4(v);
            *(f32x4*)&T[trow * 68 + a * 4] = v;
          } else if constexpr (EPI == E_MUL) {
            f32x4 h4 = tof4(*(const bf16x4*)&baux[cb]);   // gelu'(h1) bf16
            v *= h4;
            *(f32x4*)&T[trow * 68 + a * 4] = v;
          }
        }
      }

      // ---- transposed pass: pure LDS column read -> coalesced store -------
      if constexpr (TRANS) {
        asm volatile("s_waitcnt lgkmcnt(0)" ::: "memory");
        __builtin_amdgcn_sched_barrier(0);
        const int mg = m0 + wm0 + fm * 16;
        bf16x8 o0, o1;
#pragma unroll
        for (int j = 0; j < 16; ++j) {
          float vv = T[j * 68 + l];
          if (j < 8) o0[j] = (bf16)vv; else o1[j - 8] = (bf16)vv;
        }
        *(bf16x8*)&Ct[(size_t)(iB + l) * ldt + mg] = o0;
        *(bf16x8*)&Ct[(size_t)(iB + l) * ldt + mg + 8] = o1;
      }
    }
  }
}

// ---- combined TN GEMMs, L2-grouped, BK=32, with fused Q-row sums -----------
__global__ __launch_bounds__(512)
void mm_tn2c(const bf16* __restrict__ P1, int ldP1, const bf16* __restrict__ Q1, int ldQ1,
             float* __restrict__ Ga, int ldGa,
             const bf16* __restrict__ P2, int ldP2, const bf16* __restrict__ Q2, int ldQ2,
             float* __restrict__ Gb, int ldGb, int mlen,
             float* __restrict__ G4s, float* __restrict__ G2s) {
  constexpr int SBE = 128 * 32;
  __shared__ bf16 smem[4 * SBE];       // 32 KB -> 4 blocks/CU
  const int nid = xcd_chunk(blockIdx.x, gridDim.x);
  const int grp = nid / 36, pair = nid % 36;
  const int part = grp & 1, zsl = grp >> 1;
  const bf16* P; const bf16* Q; float* G; float* Gsum;
  int ldP, ldQ, ldG, p0, q0;
  if (part == 0) {
    P = P1; Q = Q1; G = Ga; ldP = ldP1; ldQ = ldQ1; ldG = ldGa; Gsum = G4s;
    p0 = (pair / 3) * 128; q0 = (pair % 3) * 128;
  } else {
    P = P2; Q = Q2; G = Gb; ldP = ldP2; ldQ = ldQ2; ldG = ldGb; Gsum = G2s;
    p0 = (pair / 12) * 128; q0 = (pair % 12) * 128;
  }
  const bool doSum = (p0 == 0);
  const int tid = threadIdx.x;
  const int mb = zsl * mlen;
  const int l = tid & 63, w = tid >> 6;
  const int a = l & 15, g = l >> 4;
  const int wp0 = (w & 1) * 64, wq0 = (w >> 1) * 32;
  const int sue = ((l & 3) ^ ((l >> 3) & 3)) * 8;
  const int fru = (g ^ ((a >> 1) & 3)) << 4;

  const bf16* pP = P + (size_t)(p0 + w * 16 + (l >> 2)) * ldP + sue;
  const bf16* pQ = Q + (size_t)(q0 + w * 16 + (l >> 2)) * ldQ + sue;

  f32x4 acc[4][2];
#pragma unroll
  for (int i = 0; i < 4; ++i)
#pragma unroll
    for (int j = 0; j < 2; ++j) acc[i][j] = f32x4{0.f, 0.f, 0.f, 0.f};
  float qsum = 0.f;
  const int sumoff = (w * 16 + (l >> 2)) * 64 + (l & 3) * 16;  // byte in Q buf

  auto stage = [&](int buf, int m0) {
    bf16* dP = smem + buf * SBE;
    bf16* dQ = smem + 2 * SBE + buf * SBE;
    gload16(pP + m0, (char*)dP + w * 1024);
    gload16(pQ + m0, (char*)dQ + w * 1024);
  };

  const int nIt = mlen >> 5;
  stage(0, mb);
  for (int it = 0; it < nIt; ++it) {
    const int cur = it & 1;
    if (it + 1 < nIt) { stage(cur ^ 1, mb + ((it + 1) << 5)); wait_vmcnt<2>(); }
    else              { wait_vmcnt<0>(); }
    __builtin_amdgcn_s_barrier();
    const bf16* bP = smem + cur * SBE;
    const bf16* bQ = smem + 2 * SBE + cur * SBE;
    {
      bf16x8 Pf[4], Qf[2];
#pragma unroll
      for (int f = 0; f < 4; ++f) {
        const int rP = wp0 + f * 16 + a;
        Pf[f] = *(const bf16x8*)((const char*)bP + rP * 64 + fru);
      }
#pragma unroll
      for (int f = 0; f < 2; ++f) {
        const int rQ = wq0 + f * 16 + a;
        Qf[f] = *(const bf16x8*)((const char*)bQ + rQ * 64 + fru);
      }
#pragma unroll
      for (int f1 = 0; f1 < 4; ++f1)
#pragma unroll
        for (int f2 = 0; f2 < 2; ++f2)
          acc[f1][f2] = __builtin_amdgcn_mfma_f32_16x16x32_bf16(Pf[f1], Qf[f2], acc[f1][f2], 0, 0, 0);
    }
    if (doSum) {   // full-row sums are invariant to the in-row unit swizzle
      bf16x8 s0 = *(const bf16x8*)((const char*)bQ + sumoff);
#pragma unroll
      for (int e = 0; e < 8; ++e) qsum += (float)s0[e];
    }
    asm volatile("s_waitcnt lgkmcnt(0)" ::: "memory");
    __builtin_amdgcn_s_barrier();
  }
#pragma unroll
  for (int f1 = 0; f1 < 4; ++f1)
#pragma unroll
    for (int f2 = 0; f2 < 2; ++f2)
#pragma unroll
      for (int r = 0; r < 4; ++r)
        atomicAdd(&G[(size_t)(p0 + wp0 + f1 * 16 + g * 4 + r) * ldG + q0 + wq0 + f2 * 16 + a],
                  acc[f1][f2][r]);
  if (doSum) {
    qsum += __shfl_xor(qsum, 1);
    qsum += __shfl_xor(qsum, 2);
    if ((l & 3) == 0) atomicAdd(&Gsum[q0 + w * 16 + (l >> 2)], qsum);
  }
}

// ---- RoPE in place ---------------------------------------------------------
__global__ __launch_bounds__(256)
void rope_kernel(bf16* __restrict__ qb, int rbase) {
  int idx = blockIdx.x * blockDim.x + threadIdx.x;
  int row = idx >> 4, hd = idx & 15;
  int j = (rbase + row) & 2047;
  float pos[3] = { (float)(j >> 8), (float)((j >> 4) & 15), (float)(j & 15) };
  const float freqs[4] = { 1.0f, 0.1f, 0.01f, 0.001f };
  bf16* p = qb + (size_t)row * 384 + hd * 24;
#pragma unroll
  for (int s = 0; s < 3; ++s) {
    bf16x8 vv = *(bf16x8*)(p + s * 8);
#pragma unroll
    for (int pr = 0; pr < 4; ++pr) {
      float ang = pos[s] * freqs[pr];
      float si, co;
      sincosf(ang, &si, &co);
      float e0 = (float)vv[2 * pr], e1 = (float)vv[2 * pr + 1];
      vv[2 * pr]     = (bf16)(e0 * co - e1 * si);
      vv[2 * pr + 1] = (bf16)(e0 * si + e1 * co);
    }
    *(bf16x8*)(p + s * 8) = vv;
  }
}

// ---- combined sumsq over G1..G4, per memory i (grid (516,5)) ---------------
__global__ __launch_bounds__(256)
void sumsq_all(const float* __restrict__ G1, const float* __restrict__ G2,
               const float* __restrict__ G3, const float* __restrict__ G4,
               float* __restrict__ red) {
  int i = blockIdx.y, bx = blockIdx.x;
  const float* base; int per, lb, nb;
  if (bx < 256)      { base = G1 + (size_t)i * 589824; per = 589824; lb = bx;       nb = 256; }
  else if (bx < 512) { base = G3 + (size_t)i * 589824; per = 589824; lb = bx - 256; nb = 256; }
  else if (bx < 514) { base = G2 + (size_t)i * 1536;   per = 1536;   lb = bx - 512; nb = 2; }
  else               { base = G4 + (size_t)i * 384;    per = 384;    lb = bx - 514; nb = 2; }
  float s = 0.f;
  for (int idx = lb * 256 + threadIdx.x; idx < per; idx += nb * 256) {
    float v = base[idx]; s += v * v;
  }
  __shared__ float sm[256];
  sm[threadIdx.x] = s; __syncthreads();
  for (int o = 128; o > 0; o >>= 1) {
    if (threadIdx.x < o) sm[threadIdx.x] += sm[threadIdx.x + o];
    __syncthreads();
  }
  if (threadIdx.x == 0) atomicAdd(&red[2 + i], sm[0]);
}

// ---- combined state update (grid (1032,5)) ---------------------------------
__global__ __launch_bounds__(256)
void update_all(float* __restrict__ SW1, float* __restrict__ SB1,
                float* __restrict__ SW2, float* __restrict__ SB2,
                const float* __restrict__ G1, const float* __restrict__ G2,
                const float* __restrict__ G3, const float* __restrict__ G4,
                const float* __restrict__ red) {
  int i = blockIdx.y, bx = blockIdx.x;
  float* S; const float* G; int per, lb, nb;
  if (bx < 512)       { S = SW1; G = G1; per = 589824; lb = bx;        nb = 512; }
  else if (bx < 1024) { S = SW2; G = G3; per = 589824; lb = bx - 512;  nb = 512; }
  else if (bx < 1028) { S = SB1; G = G2; per = 1536;   lb = bx - 1024; nb = 4; }
  else                { S = SB2; G = G4; per = 384;    lb = bx - 1028; nb = 4; }
  size_t base = (size_t)i * per;
  float em = 0.01f * red[0] * INV_CNT;
  float am = red[1] * INV_CNT;
  float norm = sqrtf(red[2 + i]);
  float sc = fminf(1.0f, 1.0f / (norm + 1e-12f));
  float ws_ = 1.0f - am;
  float gs = em * sc;
  for (int idx = lb * 256 + (int)threadIdx.x; idx < per; idx += nb * 256)
    S[base + idx] = ws_ * S[base + idx] - gs * G[base + idx];
}

// ---------------------------------------------------------------------------
extern "C" void kernel_launch(void* const* d_in, const int* in_sizes, int n_in,
                              void* d_out, int out_size, void* d_ws, size_t ws_size,
                              hipStream_t stream) {
  const float* x    = (const float*)d_in[0];
  const float* n1g  = (const float*)d_in[1];
  const float* n1b  = (const float*)d_in[2];
  const float* qW   = (const float*)d_in[3];
  const float* tW1  = (const float*)d_in[4];
  const float* tb1  = (const float*)d_in[5];
  const float* tW2  = (const float*)d_in[6];
  const float* tb2  = (const float*)d_in[7];
  const float* outW = (const float*)d_in[8];
  const float* outb = (const float*)d_in[9];
  const float* n2g  = (const float*)d_in[10];
  const float* n2b  = (const float*)d_in[11];
  const float* cW1  = (const float*)d_in[12];
  const float* cb1  = (const float*)d_in[13];
  const float* cW2  = (const float*)d_in[14];
  const float* cb2  = (const float*)d_in[15];
  float* out = (float*)d_out;

  const size_t W1SZ = 384 * 1536, W2SZ = 1536 * 384;
  const size_t STATE = 5 * W1SZ + 5 * 1536 + 5 * W2SZ + 5 * 384;
  const size_t BF_W = 21 * W1SZ + 2 * 147456;
  const size_t CHUNK_BF = 4 * (size_t)16384 * 384;                 // Yc,Kb,Vb,Kbt
  const size_t FIXEDF = 2 * STATE + 16 + BF_W / 2 + CHUNK_BF / 2;
  size_t MS = 16384;
  while (MS > 2048 && (FIXEDF + MS * 3840) * 4 > ws_size) MS >>= 1;
  if ((FIXEDF + MS * 3840) * 4 > ws_size) {
    hipMemcpyAsync(d_out, d_in[0], (size_t)25165824 * 4, hipMemcpyDeviceToDevice, stream);
    return;
  }
  const int NS = (int)(16384 / MS);
  const int iMS = (int)MS;

  float* ws = (float*)d_ws;
  size_t off = 0;
  auto alloc = [&](size_t n) { float* p = ws + off; off += n; return p; };
  auto balloc = [&](size_t n) { bf16* p = (bf16*)(ws + off); off += (n + 1) / 2; return p; };
  float* SW1 = alloc(5 * W1SZ);
  float* SB1 = alloc(5 * 1536);
  float* SW2 = alloc(5 * W2SZ);
  float* SB2 = alloc(5 * 384);
  float* G1  = alloc(5 * W1SZ);
  float* G2  = alloc(5 * 1536);
  float* G3  = alloc(5 * W2SZ);
  float* G4  = alloc(5 * 384);
  float* RED = alloc(16);
  bf16* Yc   = balloc((size_t)16384 * 384);
  bf16* Kb   = balloc((size_t)16384 * 384);
  bf16* Vb   = balloc((size_t)16384 * 384);
  bf16* Kbt  = balloc((size_t)16384 * 384);
  bf16* sw1t = balloc(5 * W1SZ);
  bf16* sw2t = balloc(5 * W2SZ);
  bf16* sw2c = balloc(5 * W2SZ);
  bf16* qwt  = balloc(147456);
  bf16* owt  = balloc(147456);
  bf16* cw1t = balloc(3 * W1SZ);
  bf16* cw2t = balloc(3 * W2SZ);
  bf16* pool = balloc(MS * 3072);
  bf16* GH1t = balloc(MS * 1536);
  bf16* DAt  = balloc(MS * 1536);
  bf16* OD   = balloc(MS * 384);
  bf16* ODt  = balloc(MS * 384);
  bf16* T2   = balloc(MS * 384);
  bf16* Tt   = balloc(MS * 384);
  bf16* H1r  = pool;                 // gelu'(h1) [m][1536]
  bf16* GH1k = pool + MS * 1536;     // gelu(h1) rm / GHv

  hipMemcpyAsync(SW1, tW1, 5 * W1SZ * 4, hipMemcpyDeviceToDevice, stream);
  hipMemcpyAsync(SB1, tb1, 5 * 1536 * 4, hipMemcpyDeviceToDevice, stream);
  hipMemcpyAsync(SW2, tW2, 5 * W2SZ * 4, hipMemcpyDeviceToDevice, stream);
  hipMemcpyAsync(SB2, tb2, 5 * 384 * 4, hipMemcpyDeviceToDevice, stream);

  trans_static<<<dim3(48, 12, 8), 256, 0, stream>>>(qW, outW, cW1, cW2, qwt, owt, cw1t, cw2t);

  const size_t grads_bytes = STATE * 4;
  const int gm  = iMS / 128;
  const int gm2 = iMS / 64;
  int mlen_t = iMS / 8; if (mlen_t < 128) mlen_t = 128;
  if (mlen_t > 2048) mlen_t = 2048;
  const int nzt = iMS / mlen_t;
  const int tn_grid = 36 * 2 * nzt;
  const float SC = 2.0f * INV_CNT;
  const size_t MSR = (size_t)iMS * 384;

  for (int c = 0; c < 4; ++c) {
    hipMemsetAsync(G1, 0, grads_bytes, stream);
    hipMemsetAsync(RED, 0, 64, stream);
    trans_state<<<dim3(48, 12, 10), 256, 0, stream>>>(SW1, SW2, sw1t, sw2t);
    copy_bf16<<<dim3(2880), 256, 0, stream>>>(SW2, sw2c, (int)(5 * W2SZ));

    ln_kernel<<<dim3(16384), dim3(64), 0, stream>>>(x, n1g, n1b, Yc, 11, c * 2048, 8192);

    // ---- gen (pair-fused fwd1 + z-batched fwd2) ----
    for (int s = 0; s < NS; ++s) {
      const bf16* Ys = Yc + (size_t)s * MSR;
      mm_fwd<E_GELU, 128><<<dim3(24, gm), 512, 0, stream>>>(Ys, 384, sw1t,
          SB1, nullptr, nullptr, nullptr, pool, nullptr, nullptr, nullptr,
          384, 3072, 0, 0.f, 0, 30, 0, 0, 0, 0, 0);
      mm_fwd<E_KV, 64><<<dim3(3, gm2, 2), 256, 0, stream>>>(pool, 3072, sw2t,
          SB2, nullptr, nullptr, nullptr, Kb + s * MSR, Vb + s * MSR, nullptr, nullptr,
          1536, 384, 0, 0.f, 0, 30, 0, 0, 1536, (long)W2SZ, 384);
      mm_fwd<E_GELU, 128><<<dim3(24, gm), 512, 0, stream>>>(Ys, 384, sw1t + 2 * W1SZ,
          SB1 + 2 * 1536, nullptr, nullptr, nullptr, pool, nullptr, nullptr, nullptr,
          384, 3072, 0, 0.f, 0, 30, 0, 0, 0, 0, 0);
      mm_fwd<E_RED2, 64><<<dim3(3, gm2, 2), 256, 0, stream>>>(pool, 3072, sw2t + 2 * W2SZ,
          SB2 + 2 * 384, nullptr, nullptr, RED, nullptr, nullptr, nullptr, nullptr,
          1536, 384, 0, 0.f, 0, 30, 0, 0, 1536, (long)W2SZ, 384);
    }

    // ---- q/out per slice ----
    for (int s = 0; s < NS; ++s) {
      const bf16* Ys = Yc + (size_t)s * MSR;
      mm_fwd<E_BF16, 64><<<dim3(3, gm2), 256, 0, stream>>>(Ys, 384, qwt,
          nullptr, nullptr, nullptr, nullptr, Tt, nullptr, nullptr, nullptr,
          384, 384, 0, 0.f, 0, 30, 0, 0, 0, 0, 0);
      rope_kernel<<<dim3(iMS / 16), 256, 0, stream>>>(Tt, s * iMS);
      mm_fwd<E_GELU, 128><<<dim3(12, gm), 512, 0, stream>>>(Tt, 384, sw1t + 4 * W1SZ,
          SB1 + 4 * 1536, nullptr, nullptr, nullptr, GH1k, nullptr, nullptr, nullptr,
          384, 1536, 0, 0.f, 0, 30, 0, 0, 0, 0, 0);
      mm_fwd<E_BF16, 64><<<dim3(3, gm2), 256, 0, stream>>>(GH1k, 1536, sw2t + 4 * W2SZ,
          SB2 + 4 * 384, nullptr, nullptr, nullptr, T2, nullptr, nullptr, nullptr,
          1536, 384, 0, 0.f, 0, 30, 0, 0, 0, 0, 0);
      mm_fwd<E_F32ADD, 64><<<dim3(3, gm2), 256, 0, stream>>>(T2, 384, owt, outb,
          nullptr, x, nullptr, nullptr, nullptr, nullptr, out,
          384, 384, 0, 0.f, s * iMS, 11, c * 2048, 8192, 0, 0, 0);
    }

    rope_kernel<<<dim3(1024), 256, 0, stream>>>(Kb, 0);
    tr_bf<<<dim3(512, 12), 256, 0, stream>>>(Kb, Kbt, 16384, 384);

    // ---- per-slice, per-memory grads ----
    for (int s = 0; s < NS; ++s) {
      const bf16* Ks = Kb + (size_t)s * MSR;
      const bf16* Vs = Vb + (size_t)s * MSR;
      for (int i = 0; i < 5; ++i) {
        if (i < 4) {
          // GHv = gelu(v@W1+b1)
          mm_fwd<E_GELU, 128><<<dim3(12, gm), 512, 0, stream>>>(Vs, 384, sw1t + i * W1SZ,
              SB1 + i * 1536, nullptr, nullptr, nullptr, GH1k, nullptr, nullptr, nullptr,
              384, 1536, 0, 0.f, 0, 30, 0, 0, 0, 0, 0);
          // k-fwd1: gelu'(h1k)->H1r, D=gelu(h1k)-GHv -> DAt(rm), GH1t
          mm_fwd<E_PAIRD, 128><<<dim3(12, gm), 512, 0, stream>>>(Ks, 384, sw1t + i * W1SZ,
              SB1 + i * 1536, GH1k, nullptr, nullptr, H1r, DAt, GH1t, nullptr,
              384, 1536, iMS, 0.f, 0, 30, 0, 0, 0, 0, 0);
          // od = D @ W2^T * sc (biases cancel)
          mm_fwd<E_SCL, 64><<<dim3(3, gm2), 256, 0, stream>>>(DAt, 1536, sw2t + i * W2SZ,
              nullptr, nullptr, nullptr, nullptr, OD, nullptr, ODt, nullptr,
              1536, 384, iMS, SC, 0, 30, 0, 0, 0, 0, 0);
        } else {
          mm_fwd<E_PAIR, 128><<<dim3(12, gm), 512, 0, stream>>>(Ks, 384, sw1t + 4 * W1SZ,
              SB1 + 4 * 1536, nullptr, nullptr, nullptr, H1r, GH1k, GH1t, nullptr,
              384, 1536, iMS, 0.f, 0, 30, 0, 0, 0, 0, 0);
          mm_fwd<E_SUB, 64><<<dim3(3, gm2), 256, 0, stream>>>(GH1k, 1536, sw2t + 4 * W2SZ,
              SB2 + 4 * 384, Vs, nullptr, nullptr, OD, nullptr, ODt, nullptr,
              1536, 384, iMS, SC, 0, 30, 0, 0, 0, 0, 0);
        }
        mm_fwd<E_MUL, 128><<<dim3(12, gm), 512, 0, stream>>>(OD, 384, sw2c + i * W2SZ,
            nullptr, H1r, nullptr, nullptr, nullptr, nullptr, DAt, nullptr,
            384, 1536, iMS, 0.f, 0, 30, 0, 0, 0, 0, 0);
        mm_tn2c<<<dim3(tn_grid), 512, 0, stream>>>(
            GH1t, iMS, ODt, iMS, G3 + i * W2SZ, 384,
            Kbt + (size_t)s * iMS, 16384, DAt, iMS, G1 + i * W1SZ, 1536, mlen_t,
            G4 + i * 384, G2 + i * 1536);
      }
    }

    sumsq_all<<<dim3(516, 5), 256, 0, stream>>>(G1, G2, G3, G4, RED);
    update_all<<<dim3(1032, 5), 256, 0, stream>>>(SW1, SB1, SW2, SB2, G1, G2, G3, G4, RED);
  }

  // ---- norm2 + 3 CMS MLP layers (+ fused final residual) ----
  const int NCS = (int)(65536 / MS);
  for (int s2 = 0; s2 < NCS; ++s2) {
    float* outp = out + (size_t)s2 * MSR;
    ln_kernel<<<dim3(iMS), dim3(64), 0, stream>>>(out, n2g, n2b, OD, 30, s2 * iMS, 0);
    bf16* hc = OD; bf16* hn = T2;
    for (int lc = 0; lc < 3; ++lc) {
      mm_fwd<E_GELU, 128><<<dim3(12, gm), 512, 0, stream>>>(hc, 384, cw1t + lc * W1SZ,
          cb1 + lc * 1536, nullptr, nullptr, nullptr, GH1k, nullptr, nullptr, nullptr,
          384, 1536, 0, 0.f, 0, 30, 0, 0, 0, 0, 0);
      if (lc < 2) {
        mm_fwd<E_BF16, 64><<<dim3(3, gm2), 256, 0, stream>>>(GH1k, 1536, cw2t + lc * W2SZ,
            cb2 + lc * 384, nullptr, nullptr, nullptr, hn, nullptr, nullptr, nullptr,
            1536, 384, 0, 0.f, 0, 30, 0, 0, 0, 0, 0);
        bf16* t = hc; hc = hn; hn = t;
      } else {
        mm_fwd<E_F32ADD, 64><<<dim3(3, gm2), 256, 0, stream>>>(GH1k, 1536, cw2t + lc * W2SZ,
            cb2 + lc * 384, nullptr, outp, nullptr, nullptr, nullptr, nullptr, outp,
            1536, 384, 0, 0.f, 0, 30, 0, 0, 0, 0, 0);
      }
    }
  }
}

// Round 17
// 8362.446 us; speedup vs baseline: 1.0603x; 1.0540x over previous
//
#include <hip/hip_runtime.h>
#include <cstddef>
#include <cstdint>

// ---------------------------------------------------------------------------
// HOPE block forward. bf16 activations + bf16-MFMA GEMMs (global_load_lds,
// XOR-swizzled LDS, counted-vmcnt pipeline, BK=32 high-occupancy cores,
// XCD-chunked swizzles, fused rowsums, algebraic target-GEMM elimination,
// shared-exp fused gelu+gelu', dual-K-loop PAIRD (GHv never materialized)).
// B=8, N=8192, DIM=384, HID=1536, 4 chunks, rows/chunk = 16384.
// ---------------------------------------------------------------------------

typedef __bf16 bf16;
typedef __bf16 bf16x4 __attribute__((ext_vector_type(4)));
typedef __bf16 bf16x8 __attribute__((ext_vector_type(8)));
typedef float  f32x4  __attribute__((ext_vector_type(4)));

constexpr float INV_CNT = 1.0f / 6291456.0f;   // 1/(16384*384)

__device__ __forceinline__ float fast_gelu(float x) {
  float u = 0.7978845608028654f * (x + 0.044715f * x * x * x);
  return x / (1.0f + __expf(-2.0f * u));
}
__device__ __forceinline__ f32x4 gelu4(f32x4 v) {
  v[0] = fast_gelu(v[0]); v[1] = fast_gelu(v[1]);
  v[2] = fast_gelu(v[2]); v[3] = fast_gelu(v[3]);
  return v;
}
// fused gelu + gelu' with a single shared exp per element
__device__ __forceinline__ void gelu_both4(f32x4 v, f32x4& g, f32x4& gp) {
#pragma unroll
  for (int e = 0; e < 4; ++e) {
    float x = v[e];
    float x2 = x * x;
    float u = 0.7978845608028654f * (x + 0.044715f * x * x2);
    float s = 1.0f / (1.0f + __expf(-2.0f * u));
    g[e]  = x * s;
    gp[e] = s + x * s * (1.0f - s) * 1.5957691216057308f * (1.0f + 0.134145f * x2);
  }
}
__device__ __forceinline__ bf16x4 tobf4(f32x4 v) {
  bf16x4 o; o[0] = (bf16)v[0]; o[1] = (bf16)v[1]; o[2] = (bf16)v[2]; o[3] = (bf16)v[3];
  return o;
}
__device__ __forceinline__ f32x4 tof4(bf16x4 v) {
  return f32x4{(float)v[0], (float)v[1], (float)v[2], (float)v[3]};
}

__device__ __forceinline__ void gload16(const bf16* g, void* lds) {
  __builtin_amdgcn_global_load_lds(
      (const __attribute__((address_space(1))) void*)g,
      (__attribute__((address_space(3))) void*)lds, 16, 0, 0);
}

// counted vmcnt wait (T4)
template <int N>
__device__ __forceinline__ void wait_vmcnt() {
  if constexpr (N == 0)      asm volatile("s_waitcnt vmcnt(0)" ::: "memory");
  else if constexpr (N == 2) asm volatile("s_waitcnt vmcnt(2)" ::: "memory");
  else if constexpr (N == 3) asm volatile("s_waitcnt vmcnt(3)" ::: "memory");
  else if constexpr (N == 4) asm volatile("s_waitcnt vmcnt(4)" ::: "memory");
  __builtin_amdgcn_sched_barrier(0);
}

// bijective XCD-chunked remap (m204)
__device__ __forceinline__ int xcd_chunk(int id, int n) {
  int q = n >> 3, r = n & 7;
  int xcd = id & 7, pos = id >> 3;
  return (xcd < r ? xcd * (q + 1) : r * (q + 1) + (xcd - r) * q) + pos;
}

// ---- LayerNorm --------------------------------------------------------------
__global__ __launch_bounds__(64)
void ln_kernel(const float* __restrict__ x, const float* __restrict__ g,
               const float* __restrict__ b, bf16* __restrict__ y,
               int shift, int base, int stride) {
  int r = blockIdx.x;
  int src = ((r >> shift) * stride) + base + (r & ((1 << shift) - 1));
  int lane = threadIdx.x;
  const float* xr = x + (size_t)src * 384;
  float vals[6];
  float s = 0.f, s2 = 0.f;
#pragma unroll
  for (int i = 0; i < 6; ++i) {
    float v = xr[lane + i * 64];
    vals[i] = v; s += v; s2 += v * v;
  }
#pragma unroll
  for (int o = 32; o > 0; o >>= 1) { s += __shfl_xor(s, o); s2 += __shfl_xor(s2, o); }
  float m = s * (1.0f / 384.0f);
  float var = s2 * (1.0f / 384.0f) - m * m;
  float rr = rsqrtf(var + 1e-5f);
  bf16* yr = y + (size_t)r * 384;
#pragma unroll
  for (int i = 0; i < 6; ++i) {
    int c = lane + i * 64;
    yr[c] = (bf16)((vals[i] - m) * rr * g[c] + b[c]);
  }
}

// ---- weight transpose core --------------------------------------------------
__device__ __forceinline__ void trw_body(const float* in, bf16* out, int R, int C,
                                         int c0, int r0, int tid) {
  __shared__ float t[32][33];
  int tr = tid >> 3, tc = (tid & 7) * 4;
  f32x4 v = *(const f32x4*)&in[(size_t)(r0 + tr) * C + c0 + tc];
  t[tr][tc + 0] = v[0]; t[tr][tc + 1] = v[1]; t[tr][tc + 2] = v[2]; t[tr][tc + 3] = v[3];
  __syncthreads();
  bf16x4 o;
  o[0] = (bf16)t[tc + 0][tr]; o[1] = (bf16)t[tc + 1][tr];
  o[2] = (bf16)t[tc + 2][tr]; o[3] = (bf16)t[tc + 3][tr];
  *(bf16x4*)&out[(size_t)(c0 + tr) * R + r0 + tc] = o;
}

__global__ __launch_bounds__(256)
void trans_state(const float* __restrict__ SW1, const float* __restrict__ SW2,
                 bf16* __restrict__ sw1t, bf16* __restrict__ sw2t) {
  int z = blockIdx.z;
  if (z < 5)
    trw_body(SW1 + (size_t)z * 589824, sw1t + (size_t)z * 589824, 384, 1536,
             blockIdx.x * 32, blockIdx.y * 32, threadIdx.x);
  else
    trw_body(SW2 + (size_t)(z - 5) * 589824, sw2t + (size_t)(z - 5) * 589824, 1536, 384,
             blockIdx.y * 32, blockIdx.x * 32, threadIdx.x);
}

__global__ __launch_bounds__(256)
void trans_static(const float* __restrict__ qW, const float* __restrict__ outW,
                  const float* __restrict__ cW1, const float* __restrict__ cW2,
                  bf16* __restrict__ qwt, bf16* __restrict__ owt,
                  bf16* __restrict__ cw1t, bf16* __restrict__ cw2t) {
  int z = blockIdx.z;
  if (z < 2) {
    if (blockIdx.x >= 12) return;
    trw_body(z ? outW : qW, z ? owt : qwt, 384, 384,
             blockIdx.x * 32, blockIdx.y * 32, threadIdx.x);
  } else if (z < 5) {
    int lc = z - 2;
    trw_body(cW1 + (size_t)lc * 589824, cw1t + (size_t)lc * 589824, 384, 1536,
             blockIdx.x * 32, blockIdx.y * 32, threadIdx.x);
  } else {
    int lc = z - 5;
    trw_body(cW2 + (size_t)lc * 589824, cw2t + (size_t)lc * 589824, 1536, 384,
             blockIdx.y * 32, blockIdx.x * 32, threadIdx.x);
  }
}

// ---- transpose bf16 [R][C] -> [C][R] (Kb -> Kbt) ---------------------------
__global__ __launch_bounds__(256)
void tr_bf(const bf16* __restrict__ in, bf16* __restrict__ out, int R, int C) {
  __shared__ bf16 t[32][36];
  int r0 = blockIdx.x * 32, c0 = blockIdx.y * 32;
  int tr = threadIdx.x >> 3, tc = (threadIdx.x & 7) * 4;
  bf16x4 v = *(const bf16x4*)&in[(size_t)(r0 + tr) * C + c0 + tc];
  t[tr][tc + 0] = v[0]; t[tr][tc + 1] = v[1]; t[tr][tc + 2] = v[2]; t[tr][tc + 3] = v[3];
  __syncthreads();
  bf16x4 o;
  o[0] = t[tc + 0][tr]; o[1] = t[tc + 1][tr]; o[2] = t[tc + 2][tr]; o[3] = t[tc + 3][tr];
  *(bf16x4*)&out[(size_t)(c0 + tr) * R + r0 + tc] = o;
}

__global__ __launch_bounds__(256)
void copy_bf16(const float* __restrict__ in, bf16* __restrict__ out, int n) {
  int i = (blockIdx.x * 256 + threadIdx.x) * 4;
  if (i < n) {
    f32x4 v = *(const f32x4*)&in[i];
    *(bf16x4*)&out[i] = tobf4(v);
  }
}

// ---- MFMA GEMM: D[i][m] = sum_k W[i][k] * Act[m][k], fused epilogues -------
// BK=32, 64B LDS rows, unit swizzle u^=((row>>1)&3).
// E_PAIRD: dual K-loop (baux = second Act = Vs); GHv held in registers.
enum { E_BF16 = 0, E_GELU, E_PAIR, E_PAIRD, E_SUB, E_SCL, E_MUL, E_F32ADD, E_KV, E_RED2 };

template <int EPI, int BM>
__global__ __launch_bounds__(BM == 128 ? 512 : 256)
void mm_fwd(const bf16* __restrict__ Act, int lda, const bf16* __restrict__ W,
            const float* __restrict__ bias, const bf16* __restrict__ baux,
            const float* __restrict__ faux, float* __restrict__ red,
            bf16* __restrict__ Cb, bf16* __restrict__ C2, bf16* __restrict__ Ct,
            float* __restrict__ Cf, int K, int ldc, int ldt, float scale,
            int croff, int cshift, int cbase, int cstride,
            long zA, long zW, int zB) {
  constexpr int NW = (BM == 128) ? 8 : 4;
  constexpr int NFM = 2;
  constexpr int TW = 8 / NW;
  constexpr int TA = (BM / 16) / NW;
  constexpr int LPT = TW + TA;
  constexpr int SWE = 128 * 32;
  constexpr int SAE = BM * 32;
  constexpr int BUFE = 2 * (SWE + SAE);
  constexpr int SLABE = NW * 16 * 68 * 2;
  constexpr int SMEME = (BUFE > SLABE) ? BUFE : SLABE;
  constexpr bool TRANS = (EPI == E_PAIR || EPI == E_SUB || EPI == E_SCL || EPI == E_MUL);
  __shared__ bf16 smem[SMEME];
  const int z = blockIdx.z;
  Act += (size_t)z * zA;
  W   += (size_t)z * zW;
  if (bias) bias += (size_t)z * zB;
  const int nx = gridDim.x;
  const int nid = xcd_chunk(blockIdx.y * nx + blockIdx.x, nx * gridDim.y);
  const int m0 = (nid / nx) * BM, i0 = (nid % nx) * 128;
  const int tid = threadIdx.x;
  const int l = tid & 63, w = tid >> 6;
  const int a = l & 15, g = l >> 4;
  const int wi0 = (w & 1) * 64, wm0 = (w >> 1) * 32;
  const int srow = l >> 2;
  const int sue = ((l & 3) ^ ((l >> 3) & 3)) * 8;
  const int fru = (g ^ ((a >> 1) & 3)) << 4;

  const bf16* wp = W   + (size_t)(i0 + srow) * K   + sue;
  const bf16* ap = Act + (size_t)(m0 + srow) * lda + sue;

  f32x4 acc[4][NFM];
#pragma unroll
  for (int i = 0; i < 4; ++i)
#pragma unroll
    for (int j = 0; j < NFM; ++j) acc[i][j] = f32x4{0.f, 0.f, 0.f, 0.f};

  // proven pipelined K-loop (stage -> counted vmcnt -> barrier -> MFMA ->
  // lgkm -> barrier), parameterized on the Act base pointer
  auto run_loop = [&](const bf16* ab) {
    auto stg = [&](int buf, int k0) {
      bf16* dW = smem + buf * SWE;
      bf16* dA = smem + 2 * SWE + buf * SAE;
#pragma unroll
      for (int t = 0; t < TW; ++t) {
        const int seg = w * TW + t;
        gload16(wp + (size_t)(seg * 16) * K + k0, (char*)dW + seg * 1024);
      }
#pragma unroll
      for (int t = 0; t < TA; ++t) {
        const int seg = w * TA + t;
        gload16(ab + (size_t)(seg * 16) * lda + k0, (char*)dA + seg * 1024);
      }
    };
    const int nIt = K >> 5;
    stg(0, 0);
    for (int it = 0; it < nIt; ++it) {
      const int cur = it & 1;
      if (it + 1 < nIt) { stg(cur ^ 1, (it + 1) << 5); wait_vmcnt<LPT>(); }
      else              { wait_vmcnt<0>(); }
      __builtin_amdgcn_s_barrier();
      const bf16* bW = smem + cur * SWE;
      const bf16* bA = smem + 2 * SWE + cur * SAE;
      {
        bf16x8 Af[4], Bf[NFM];
#pragma unroll
        for (int f = 0; f < 4; ++f) {
          const int rW = wi0 + f * 16 + a;
          Af[f] = *(const bf16x8*)((const char*)bW + rW * 64 + fru);
        }
#pragma unroll
        for (int f = 0; f < NFM; ++f) {
          const int rA = wm0 + f * 16 + a;
          Bf[f] = *(const bf16x8*)((const char*)bA + rA * 64 + fru);
        }
#pragma unroll
        for (int fi = 0; fi < 4; ++fi)
#pragma unroll
          for (int fm = 0; fm < NFM; ++fm)
            acc[fi][fm] = __builtin_amdgcn_mfma_f32_16x16x32_bf16(Af[fi], Bf[fm], acc[fi][fm], 0, 0, 0);
      }
      asm volatile("s_waitcnt lgkmcnt(0)" ::: "memory");
      __builtin_amdgcn_s_barrier();
    }
  };

  bf16x4 ghv[4][NFM];   // only live for E_PAIRD
  if constexpr (EPI == E_PAIRD) {
    // loop 1: Vs -> ghv = bf16(gelu(acc + bias)) held in registers
    run_loop(baux + (size_t)(m0 + srow) * lda + sue);
#pragma unroll
    for (int fi = 0; fi < 4; ++fi)
#pragma unroll
      for (int fm = 0; fm < NFM; ++fm) {
        f32x4 bb = *(const f32x4*)&bias[i0 + wi0 + fi * 16 + g * 4];
        ghv[fi][fm] = tobf4(gelu4(acc[fi][fm] + bb));
        acc[fi][fm] = f32x4{0.f, 0.f, 0.f, 0.f};
      }
  }
  run_loop(ap);

  if constexpr (EPI == E_RED2) {
    float ssum = 0.f;
#pragma unroll
    for (int fi = 0; fi < 4; ++fi) {
      f32x4 b4 = *(const f32x4*)&bias[i0 + wi0 + fi * 16 + g * 4];
#pragma unroll
      for (int fm = 0; fm < NFM; ++fm)
#pragma unroll
        for (int r = 0; r < 4; ++r) {
          float vv = acc[fi][fm][r] + b4[r];
          if (z == 0) ssum += fmaxf(vv, 0.f) + log1pf(__expf(-fabsf(vv)));
          else        ssum += 1.0f / (1.0f + __expf(-vv));
        }
    }
#pragma unroll
    for (int o = 32; o > 0; o >>= 1) ssum += __shfl_xor(ssum, o);
    float* wred = (float*)smem;
    if (l == 0) wred[w] = ssum;
    __syncthreads();
    if (tid == 0) {
      float t2 = 0.f;
      for (int q = 0; q < NW; ++q) t2 += wred[q];
      atomicAdd(&red[z], t2);
    }
    return;
  } else {
    float* T = (float*)smem + w * (16 * 68);
    const int iB = i0 + wi0;
    f32x4 b4 = f32x4{0.f, 0.f, 0.f, 0.f};
    if (bias) b4 = *(const f32x4*)&bias[iB + a * 4];
#pragma unroll
    for (int fm = 0; fm < NFM; ++fm) {
      if constexpr (EPI == E_PAIRD) {
        // fragment-domain math: gp, gv, d = gv - ghv (all thread-private)
        f32x4 gvk[4], gpk[4], ddk[4];
#pragma unroll
        for (int fi = 0; fi < 4; ++fi) {
          f32x4 bb = *(const f32x4*)&bias[iB + fi * 16 + g * 4];
          f32x4 vv = acc[fi][fm] + bb;
          f32x4 gv, gp;
          gelu_both4(vv, gv, gp);
          gvk[fi] = gv; gpk[fi] = gp;
          ddk[fi] = gv - tof4(ghv[fi][fm]);
        }
        // bounce 1: gp -> H1r row-major (Cb)
#pragma unroll
        for (int fi = 0; fi < 4; ++fi)
          *(f32x4*)&T[a * 68 + fi * 16 + g * 4] = gpk[fi];
        asm volatile("s_waitcnt lgkmcnt(0)" ::: "memory");
        __builtin_amdgcn_sched_barrier(0);
#pragma unroll
        for (int q = 0; q < 4; ++q) {
          const int ml = wm0 + fm * 16 + q * 4 + g;
          const size_t cb = (size_t)(m0 + ml) * ldc + iB + a * 4;
          *(bf16x4*)&Cb[cb] = tobf4(*(const f32x4*)&T[(q * 4 + g) * 68 + a * 4]);
        }
        asm volatile("s_waitcnt lgkmcnt(0)" ::: "memory");
        __builtin_amdgcn_sched_barrier(0);
        // bounce 2: d -> DAt row-major (C2)
#pragma unroll
        for (int fi = 0; fi < 4; ++fi)
          *(f32x4*)&T[a * 68 + fi * 16 + g * 4] = ddk[fi];
        asm volatile("s_waitcnt lgkmcnt(0)" ::: "memory");
        __builtin_amdgcn_sched_barrier(0);
#pragma unroll
        for (int q = 0; q < 4; ++q) {
          const int ml = wm0 + fm * 16 + q * 4 + g;
          const size_t cb = (size_t)(m0 + ml) * ldc + iB + a * 4;
          *(bf16x4*)&C2[cb] = tobf4(*(const f32x4*)&T[(q * 4 + g) * 68 + a * 4]);
        }
        asm volatile("s_waitcnt lgkmcnt(0)" ::: "memory");
        __builtin_amdgcn_sched_barrier(0);
        // bounce 3: gv -> GH1t transposed (Ct)
#pragma unroll
        for (int fi = 0; fi < 4; ++fi)
          *(f32x4*)&T[a * 68 + fi * 16 + g * 4] = gvk[fi];
        asm volatile("s_waitcnt lgkmcnt(0)" ::: "memory");
        __builtin_amdgcn_sched_barrier(0);
        {
          const int mg = m0 + wm0 + fm * 16;
          bf16x8 o0, o1;
#pragma unroll
          for (int j = 0; j < 16; ++j) {
            float vv = T[j * 68 + l];
            if (j < 8) o0[j] = (bf16)vv; else o1[j - 8] = (bf16)vv;
          }
          *(bf16x8*)&Ct[(size_t)(iB + l) * ldt + mg] = o0;
          *(bf16x8*)&Ct[(size_t)(iB + l) * ldt + mg + 8] = o1;
        }
        continue;
      }

#pragma unroll
      for (int fi = 0; fi < 4; ++fi)
        *(f32x4*)&T[a * 68 + fi * 16 + g * 4] = acc[fi][fm];
      asm volatile("s_waitcnt lgkmcnt(0)" ::: "memory");
      __builtin_amdgcn_sched_barrier(0);

      // ---- row-major pass: coalesced aux reads, all ops here --------------
#pragma unroll
      for (int q = 0; q < 4; ++q) {
        const int ml = wm0 + fm * 16 + q * 4 + g;
        const int trow = q * 4 + g;
        f32x4 v = *(const f32x4*)&T[trow * 68 + a * 4];
        v += b4;
        if constexpr (EPI == E_F32ADD) {
          const int rr = croff + m0 + ml;
          const int crow = ((rr >> cshift) * cstride) + cbase + (rr & ((1 << cshift) - 1));
          const size_t cb = (size_t)crow * ldc + iB + a * 4;
          v += *(const f32x4*)&faux[cb];
          *(f32x4*)&Cf[cb] = v;
        } else {
          const size_t cb = (size_t)(m0 + ml) * ldc + iB + a * 4;
          if constexpr (EPI == E_BF16) {
            *(bf16x4*)&Cb[cb] = tobf4(v);
          } else if constexpr (EPI == E_KV) {
            bf16* DST = (z == 0) ? Cb : C2;
            *(bf16x4*)&DST[cb] = tobf4(v);
          } else if constexpr (EPI == E_GELU) {
            *(bf16x4*)&Cb[cb] = tobf4(gelu4(v));
          } else if constexpr (EPI == E_PAIR) {
            f32x4 gv, gp;
            gelu_both4(v, gv, gp);
            *(bf16x4*)&Cb[cb] = tobf4(gp);
            *(bf16x4*)&C2[cb] = tobf4(gv);
            *(f32x4*)&T[trow * 68 + a * 4] = gv;
          } else if constexpr (EPI == E_SUB) {
            f32x4 t4 = tof4(*(const bf16x4*)&baux[cb]);
            v = (v - t4) * scale;
            *(bf16x4*)&Cb[cb] = tobf4(v);
            *(f32x4*)&T[trow * 68 + a * 4] = v;
          } else if constexpr (EPI == E_SCL) {
            v = v * scale;
            *(bf16x4*)&Cb[cb] = tobf4(v);
            *(f32x4*)&T[trow * 68 + a * 4] = v;
          } else if constexpr (EPI == E_MUL) {
            f32x4 h4 = tof4(*(const bf16x4*)&baux[cb]);   // gelu'(h1) bf16
            v *= h4;
            *(f32x4*)&T[trow * 68 + a * 4] = v;
          }
        }
      }

      // ---- transposed pass: pure LDS column read -> coalesced store -------
      if constexpr (TRANS) {
        asm volatile("s_waitcnt lgkmcnt(0)" ::: "memory");
        __builtin_amdgcn_sched_barrier(0);
        const int mg = m0 + wm0 + fm * 16;
        bf16x8 o0, o1;
#pragma unroll
        for (int j = 0; j < 16; ++j) {
          float vv = T[j * 68 + l];
          if (j < 8) o0[j] = (bf16)vv; else o1[j - 8] = (bf16)vv;
        }
        *(bf16x8*)&Ct[(size_t)(iB + l) * ldt + mg] = o0;
        *(bf16x8*)&Ct[(size_t)(iB + l) * ldt + mg + 8] = o1;
      }
    }
  }
}

// ---- combined TN GEMMs, L2-grouped, BK=32, with fused Q-row sums -----------
__global__ __launch_bounds__(512)
void mm_tn2c(const bf16* __restrict__ P1, int ldP1, const bf16* __restrict__ Q1, int ldQ1,
             float* __restrict__ Ga, int ldGa,
             const bf16* __restrict__ P2, int ldP2, const bf16* __restrict__ Q2, int ldQ2,
             float* __restrict__ Gb, int ldGb, int mlen,
             float* __restrict__ G4s, float* __restrict__ G2s) {
  constexpr int SBE = 128 * 32;
  __shared__ bf16 smem[4 * SBE];       // 32 KB -> 4 blocks/CU
  const int nid = xcd_chunk(blockIdx.x, gridDim.x);
  const int grp = nid / 36, pair = nid % 36;
  const int part = grp & 1, zsl = grp >> 1;
  const bf16* P; const bf16* Q; float* G; float* Gsum;
  int ldP, ldQ, ldG, p0, q0;
  if (part == 0) {
    P = P1; Q = Q1; G = Ga; ldP = ldP1; ldQ = ldQ1; ldG = ldGa; Gsum = G4s;
    p0 = (pair / 3) * 128; q0 = (pair % 3) * 128;
  } else {
    P = P2; Q = Q2; G = Gb; ldP = ldP2; ldQ = ldQ2; ldG = ldGb; Gsum = G2s;
    p0 = (pair / 12) * 128; q0 = (pair % 12) * 128;
  }
  const bool doSum = (p0 == 0);
  const int tid = threadIdx.x;
  const int mb = zsl * mlen;
  const int l = tid & 63, w = tid >> 6;
  const int a = l & 15, g = l >> 4;
  const int wp0 = (w & 1) * 64, wq0 = (w >> 1) * 32;
  const int sue = ((l & 3) ^ ((l >> 3) & 3)) * 8;
  const int fru = (g ^ ((a >> 1) & 3)) << 4;

  const bf16* pP = P + (size_t)(p0 + w * 16 + (l >> 2)) * ldP + sue;
  const bf16* pQ = Q + (size_t)(q0 + w * 16 + (l >> 2)) * ldQ + sue;

  f32x4 acc[4][2];
#pragma unroll
  for (int i = 0; i < 4; ++i)
#pragma unroll
    for (int j = 0; j < 2; ++j) acc[i][j] = f32x4{0.f, 0.f, 0.f, 0.f};
  float qsum = 0.f;
  const int sumoff = (w * 16 + (l >> 2)) * 64 + (l & 3) * 16;  // byte in Q buf

  auto stage = [&](int buf, int m0) {
    bf16* dP = smem + buf * SBE;
    bf16* dQ = smem + 2 * SBE + buf * SBE;
    gload16(pP + m0, (char*)dP + w * 1024);
    gload16(pQ + m0, (char*)dQ + w * 1024);
  };

  const int nIt = mlen >> 5;
  stage(0, mb);
  for (int it = 0; it < nIt; ++it) {
    const int cur = it & 1;
    if (it + 1 < nIt) { stage(cur ^ 1, mb + ((it + 1) << 5)); wait_vmcnt<2>(); }
    else              { wait_vmcnt<0>(); }
    __builtin_amdgcn_s_barrier();
    const bf16* bP = smem + cur * SBE;
    const bf16* bQ = smem + 2 * SBE + cur * SBE;
    {
      bf16x8 Pf[4], Qf[2];
#pragma unroll
      for (int f = 0; f < 4; ++f) {
        const int rP = wp0 + f * 16 + a;
        Pf[f] = *(const bf16x8*)((const char*)bP + rP * 64 + fru);
      }
#pragma unroll
      for (int f = 0; f < 2; ++f) {
        const int rQ = wq0 + f * 16 + a;
        Qf[f] = *(const bf16x8*)((const char*)bQ + rQ * 64 + fru);
      }
#pragma unroll
      for (int f1 = 0; f1 < 4; ++f1)
#pragma unroll
        for (int f2 = 0; f2 < 2; ++f2)
          acc[f1][f2] = __builtin_amdgcn_mfma_f32_16x16x32_bf16(Pf[f1], Qf[f2], acc[f1][f2], 0, 0, 0);
    }
    if (doSum) {   // full-row sums are invariant to the in-row unit swizzle
      bf16x8 s0 = *(const bf16x8*)((const char*)bQ + sumoff);
#pragma unroll
      for (int e = 0; e < 8; ++e) qsum += (float)s0[e];
    }
    asm volatile("s_waitcnt lgkmcnt(0)" ::: "memory");
    __builtin_amdgcn_s_barrier();
  }
#pragma unroll
  for (int f1 = 0; f1 < 4; ++f1)
#pragma unroll
    for (int f2 = 0; f2 < 2; ++f2)
#pragma unroll
      for (int r = 0; r < 4; ++r)
        atomicAdd(&G[(size_t)(p0 + wp0 + f1 * 16 + g * 4 + r) * ldG + q0 + wq0 + f2 * 16 + a],
                  acc[f1][f2][r]);
  if (doSum) {
    qsum += __shfl_xor(qsum, 1);
    qsum += __shfl_xor(qsum, 2);
    if ((l & 3) == 0) atomicAdd(&Gsum[q0 + w * 16 + (l >> 2)], qsum);
  }
}

// ---- RoPE in place ---------------------------------------------------------
__global__ __launch_bounds__(256)
void rope_kernel(bf16* __restrict__ qb, int rbase) {
  int idx = blockIdx.x * blockDim.x + threadIdx.x;
  int row = idx >> 4, hd = idx & 15;
  int j = (rbase + row) & 2047;
  float pos[3] = { (float)(j >> 8), (float)((j >> 4) & 15), (float)(j & 15) };
  const float freqs[4] = { 1.0f, 0.1f, 0.01f, 0.001f };
  bf16* p = qb + (size_t)row * 384 + hd * 24;
#pragma unroll
  for (int s = 0; s < 3; ++s) {
    bf16x8 vv = *(bf16x8*)(p + s * 8);
#pragma unroll
    for (int pr = 0; pr < 4; ++pr) {
      float ang = pos[s] * freqs[pr];
      float si, co;
      sincosf(ang, &si, &co);
      float e0 = (float)vv[2 * pr], e1 = (float)vv[2 * pr + 1];
      vv[2 * pr]     = (bf16)(e0 * co - e1 * si);
      vv[2 * pr + 1] = (bf16)(e0 * si + e1 * co);
    }
    *(bf16x8*)(p + s * 8) = vv;
  }
}

// ---- combined sumsq over G1..G4, per memory i (grid (516,5)) ---------------
__global__ __launch_bounds__(256)
void sumsq_all(const float* __restrict__ G1, const float* __restrict__ G2,
               const float* __restrict__ G3, const float* __restrict__ G4,
               float* __restrict__ red) {
  int i = blockIdx.y, bx = blockIdx.x;
  const float* base; int per, lb, nb;
  if (bx < 256)      { base = G1 + (size_t)i * 589824; per = 589824; lb = bx;       nb = 256; }
  else if (bx < 512) { base = G3 + (size_t)i * 589824; per = 589824; lb = bx - 256; nb = 256; }
  else if (bx < 514) { base = G2 + (size_t)i * 1536;   per = 1536;   lb = bx - 512; nb = 2; }
  else               { base = G4 + (size_t)i * 384;    per = 384;    lb = bx - 514; nb = 2; }
  float s = 0.f;
  for (int idx = lb * 256 + threadIdx.x; idx < per; idx += nb * 256) {
    float v = base[idx]; s += v * v;
  }
  __shared__ float sm[256];
  sm[threadIdx.x] = s; __syncthreads();
  for (int o = 128; o > 0; o >>= 1) {
    if (threadIdx.x < o) sm[threadIdx.x] += sm[threadIdx.x + o];
    __syncthreads();
  }
  if (threadIdx.x == 0) atomicAdd(&red[2 + i], sm[0]);
}

// ---- combined state update (grid (1032,5)) ---------------------------------
__global__ __launch_bounds__(256)
void update_all(float* __restrict__ SW1, float* __restrict__ SB1,
                float* __restrict__ SW2, float* __restrict__ SB2,
                const float* __restrict__ G1, const float* __restrict__ G2,
                const float* __restrict__ G3, const float* __restrict__ G4,
                const float* __restrict__ red) {
  int i = blockIdx.y, bx = blockIdx.x;
  float* S; const float* G; int per, lb, nb;
  if (bx < 512)       { S = SW1; G = G1; per = 589824; lb = bx;        nb = 512; }
  else if (bx < 1024) { S = SW2; G = G3; per = 589824; lb = bx - 512;  nb = 512; }
  else if (bx < 1028) { S = SB1; G = G2; per = 1536;   lb = bx - 1024; nb = 4; }
  else                { S = SB2; G = G4; per = 384;    lb = bx - 1028; nb = 4; }
  size_t base = (size_t)i * per;
  float em = 0.01f * red[0] * INV_CNT;
  float am = red[1] * INV_CNT;
  float norm = sqrtf(red[2 + i]);
  float sc = fminf(1.0f, 1.0f / (norm + 1e-12f));
  float ws_ = 1.0f - am;
  float gs = em * sc;
  for (int idx = lb * 256 + (int)threadIdx.x; idx < per; idx += nb * 256)
    S[base + idx] = ws_ * S[base + idx] - gs * G[base + idx];
}

// ---------------------------------------------------------------------------
extern "C" void kernel_launch(void* const* d_in, const int* in_sizes, int n_in,
                              void* d_out, int out_size, void* d_ws, size_t ws_size,
                              hipStream_t stream) {
  const float* x    = (const float*)d_in[0];
  const float* n1g  = (const float*)d_in[1];
  const float* n1b  = (const float*)d_in[2];
  const float* qW   = (const float*)d_in[3];
  const float* tW1  = (const float*)d_in[4];
  const float* tb1  = (const float*)d_in[5];
  const float* tW2  = (const float*)d_in[6];
  const float* tb2  = (const float*)d_in[7];
  const float* outW = (const float*)d_in[8];
  const float* outb = (const float*)d_in[9];
  const float* n2g  = (const float*)d_in[10];
  const float* n2b  = (const float*)d_in[11];
  const float* cW1  = (const float*)d_in[12];
  const float* cb1  = (const float*)d_in[13];
  const float* cW2  = (const float*)d_in[14];
  const float* cb2  = (const float*)d_in[15];
  float* out = (float*)d_out;

  const size_t W1SZ = 384 * 1536, W2SZ = 1536 * 384;
  const size_t STATE = 5 * W1SZ + 5 * 1536 + 5 * W2SZ + 5 * 384;
  const size_t BF_W = 21 * W1SZ + 2 * 147456;
  const size_t CHUNK_BF = 4 * (size_t)16384 * 384;                 // Yc,Kb,Vb,Kbt
  const size_t FIXEDF = 2 * STATE + 16 + BF_W / 2 + CHUNK_BF / 2;
  size_t MS = 16384;
  while (MS > 2048 && (FIXEDF + MS * 3840) * 4 > ws_size) MS >>= 1;
  if ((FIXEDF + MS * 3840) * 4 > ws_size) {
    hipMemcpyAsync(d_out, d_in[0], (size_t)25165824 * 4, hipMemcpyDeviceToDevice, stream);
    return;
  }
  const int NS = (int)(16384 / MS);
  const int iMS = (int)MS;

  float* ws = (float*)d_ws;
  size_t off = 0;
  auto alloc = [&](size_t n) { float* p = ws + off; off += n; return p; };
  auto balloc = [&](size_t n) { bf16* p = (bf16*)(ws + off); off += (n + 1) / 2; return p; };
  float* SW1 = alloc(5 * W1SZ);
  float* SB1 = alloc(5 * 1536);
  float* SW2 = alloc(5 * W2SZ);
  float* SB2 = alloc(5 * 384);
  float* G1  = alloc(5 * W1SZ);
  float* G2  = alloc(5 * 1536);
  float* G3  = alloc(5 * W2SZ);
  float* G4  = alloc(5 * 384);
  float* RED = alloc(16);
  bf16* Yc   = balloc((size_t)16384 * 384);
  bf16* Kb   = balloc((size_t)16384 * 384);
  bf16* Vb   = balloc((size_t)16384 * 384);
  bf16* Kbt  = balloc((size_t)16384 * 384);
  bf16* sw1t = balloc(5 * W1SZ);
  bf16* sw2t = balloc(5 * W2SZ);
  bf16* sw2c = balloc(5 * W2SZ);
  bf16* qwt  = balloc(147456);
  bf16* owt  = balloc(147456);
  bf16* cw1t = balloc(3 * W1SZ);
  bf16* cw2t = balloc(3 * W2SZ);
  bf16* pool = balloc(MS * 3072);
  bf16* GH1t = balloc(MS * 1536);
  bf16* DAt  = balloc(MS * 1536);
  bf16* OD   = balloc(MS * 384);
  bf16* ODt  = balloc(MS * 384);
  bf16* T2   = balloc(MS * 384);
  bf16* Tt   = balloc(MS * 384);
  bf16* H1r  = pool;                 // gelu'(h1) [m][1536]
  bf16* GH1k = pool + MS * 1536;     // gelu(h1) rm (i=4 / q / CMS paths)

  hipMemcpyAsync(SW1, tW1, 5 * W1SZ * 4, hipMemcpyDeviceToDevice, stream);
  hipMemcpyAsync(SB1, tb1, 5 * 1536 * 4, hipMemcpyDeviceToDevice, stream);
  hipMemcpyAsync(SW2, tW2, 5 * W2SZ * 4, hipMemcpyDeviceToDevice, stream);
  hipMemcpyAsync(SB2, tb2, 5 * 384 * 4, hipMemcpyDeviceToDevice, stream);

  trans_static<<<dim3(48, 12, 8), 256, 0, stream>>>(qW, outW, cW1, cW2, qwt, owt, cw1t, cw2t);

  const size_t grads_bytes = STATE * 4;
  const int gm  = iMS / 128;
  const int gm2 = iMS / 64;
  int mlen_t = iMS / 8; if (mlen_t < 128) mlen_t = 128;
  if (mlen_t > 2048) mlen_t = 2048;
  const int nzt = iMS / mlen_t;
  const int tn_grid = 36 * 2 * nzt;
  const float SC = 2.0f * INV_CNT;
  const size_t MSR = (size_t)iMS * 384;

  for (int c = 0; c < 4; ++c) {
    hipMemsetAsync(G1, 0, grads_bytes, stream);
    hipMemsetAsync(RED, 0, 64, stream);
    trans_state<<<dim3(48, 12, 10), 256, 0, stream>>>(SW1, SW2, sw1t, sw2t);
    copy_bf16<<<dim3(2880), 256, 0, stream>>>(SW2, sw2c, (int)(5 * W2SZ));

    ln_kernel<<<dim3(16384), dim3(64), 0, stream>>>(x, n1g, n1b, Yc, 11, c * 2048, 8192);

    // ---- gen (pair-fused fwd1 + z-batched fwd2) ----
    for (int s = 0; s < NS; ++s) {
      const bf16* Ys = Yc + (size_t)s * MSR;
      mm_fwd<E_GELU, 128><<<dim3(24, gm), 512, 0, stream>>>(Ys, 384, sw1t,
          SB1, nullptr, nullptr, nullptr, pool, nullptr, nullptr, nullptr,
          384, 3072, 0, 0.f, 0, 30, 0, 0, 0, 0, 0);
      mm_fwd<E_KV, 64><<<dim3(3, gm2, 2), 256, 0, stream>>>(pool, 3072, sw2t,
          SB2, nullptr, nullptr, nullptr, Kb + s * MSR, Vb + s * MSR, nullptr, nullptr,
          1536, 384, 0, 0.f, 0, 30, 0, 0, 1536, (long)W2SZ, 384);
      mm_fwd<E_GELU, 128><<<dim3(24, gm), 512, 0, stream>>>(Ys, 384, sw1t + 2 * W1SZ,
          SB1 + 2 * 1536, nullptr, nullptr, nullptr, pool, nullptr, nullptr, nullptr,
          384, 3072, 0, 0.f, 0, 30, 0, 0, 0, 0, 0);
      mm_fwd<E_RED2, 64><<<dim3(3, gm2, 2), 256, 0, stream>>>(pool, 3072, sw2t + 2 * W2SZ,
          SB2 + 2 * 384, nullptr, nullptr, RED, nullptr, nullptr, nullptr, nullptr,
          1536, 384, 0, 0.f, 0, 30, 0, 0, 1536, (long)W2SZ, 384);
    }

    // ---- q/out per slice ----
    for (int s = 0; s < NS; ++s) {
      const bf16* Ys = Yc + (size_t)s * MSR;
      mm_fwd<E_BF16, 64><<<dim3(3, gm2), 256, 0, stream>>>(Ys, 384, qwt,
          nullptr, nullptr, nullptr, nullptr, Tt, nullptr, nullptr, nullptr,
          384, 384, 0, 0.f, 0, 30, 0, 0, 0, 0, 0);
      rope_kernel<<<dim3(iMS / 16), 256, 0, stream>>>(Tt, s * iMS);
      mm_fwd<E_GELU, 128><<<dim3(12, gm), 512, 0, stream>>>(Tt, 384, sw1t + 4 * W1SZ,
          SB1 + 4 * 1536, nullptr, nullptr, nullptr, GH1k, nullptr, nullptr, nullptr,
          384, 1536, 0, 0.f, 0, 30, 0, 0, 0, 0, 0);
      mm_fwd<E_BF16, 64><<<dim3(3, gm2), 256, 0, stream>>>(GH1k, 1536, sw2t + 4 * W2SZ,
          SB2 + 4 * 384, nullptr, nullptr, nullptr, T2, nullptr, nullptr, nullptr,
          1536, 384, 0, 0.f, 0, 30, 0, 0, 0, 0, 0);
      mm_fwd<E_F32ADD, 64><<<dim3(3, gm2), 256, 0, stream>>>(T2, 384, owt, outb,
          nullptr, x, nullptr, nullptr, nullptr, nullptr, out,
          384, 384, 0, 0.f, s * iMS, 11, c * 2048, 8192, 0, 0, 0);
    }

    rope_kernel<<<dim3(1024), 256, 0, stream>>>(Kb, 0);
    tr_bf<<<dim3(512, 12), 256, 0, stream>>>(Kb, Kbt, 16384, 384);

    // ---- per-slice, per-memory grads ----
    for (int s = 0; s < NS; ++s) {
      const bf16* Ks = Kb + (size_t)s * MSR;
      const bf16* Vs = Vb + (size_t)s * MSR;
      for (int i = 0; i < 5; ++i) {
        if (i < 4) {
          // dual-loop PAIRD: loop1 on Vs (ghv in regs), loop2 on Ks;
          // emits gelu'->H1r, D=gelu_k-gelu_v -> DAt(rm), GH1t(transposed)
          mm_fwd<E_PAIRD, 128><<<dim3(12, gm), 512, 0, stream>>>(Ks, 384, sw1t + i * W1SZ,
              SB1 + i * 1536, Vs, nullptr, nullptr, H1r, DAt, GH1t, nullptr,
              384, 1536, iMS, 0.f, 0, 30, 0, 0, 0, 0, 0);
          // od = D @ W2^T * sc (biases cancel)
          mm_fwd<E_SCL, 64><<<dim3(3, gm2), 256, 0, stream>>>(DAt, 1536, sw2t + i * W2SZ,
              nullptr, nullptr, nullptr, nullptr, OD, nullptr, ODt, nullptr,
              1536, 384, iMS, SC, 0, 30, 0, 0, 0, 0, 0);
        } else {
          mm_fwd<E_PAIR, 128><<<dim3(12, gm), 512, 0, stream>>>(Ks, 384, sw1t + 4 * W1SZ,
              SB1 + 4 * 1536, nullptr, nullptr, nullptr, H1r, GH1k, GH1t, nullptr,
              384, 1536, iMS, 0.f, 0, 30, 0, 0, 0, 0, 0);
          mm_fwd<E_SUB, 64><<<dim3(3, gm2), 256, 0, stream>>>(GH1k, 1536, sw2t + 4 * W2SZ,
              SB2 + 4 * 384, Vs, nullptr, nullptr, OD, nullptr, ODt, nullptr,
              1536, 384, iMS, SC, 0, 30, 0, 0, 0, 0, 0);
        }
        mm_fwd<E_MUL, 128><<<dim3(12, gm), 512, 0, stream>>>(OD, 384, sw2c + i * W2SZ,
            nullptr, H1r, nullptr, nullptr, nullptr, nullptr, DAt, nullptr,
            384, 1536, iMS, 0.f, 0, 30, 0, 0, 0, 0, 0);
        mm_tn2c<<<dim3(tn_grid), 512, 0, stream>>>(
            GH1t, iMS, ODt, iMS, G3 + i * W2SZ, 384,
            Kbt + (size_t)s * iMS, 16384, DAt, iMS, G1 + i * W1SZ, 1536, mlen_t,
            G4 + i * 384, G2 + i * 1536);
      }
    }

    sumsq_all<<<dim3(516, 5), 256, 0, stream>>>(G1, G2, G3, G4, RED);
    update_all<<<dim3(1032, 5), 256, 0, stream>>>(SW1, SB1, SW2, SB2, G1, G2, G3, G4, RED);
  }

  // ---- norm2 + 3 CMS MLP layers (+ fused final residual) ----
  const int NCS = (int)(65536 / MS);
  for (int s2 = 0; s2 < NCS; ++s2) {
    float* outp = out + (size_t)s2 * MSR;
    ln_kernel<<<dim3(iMS), dim3(64), 0, stream>>>(out, n2g, n2b, OD, 30, s2 * iMS, 0);
    bf16* hc = OD; bf16* hn = T2;
    for (int lc = 0; lc < 3; ++lc) {
      mm_fwd<E_GELU, 128><<<dim3(12, gm), 512, 0, stream>>>(hc, 384, cw1t + lc * W1SZ,
          cb1 + lc * 1536, nullptr, nullptr, nullptr, GH1k, nullptr, nullptr, nullptr,
          384, 1536, 0, 0.f, 0, 30, 0, 0, 0, 0, 0);
      if (lc < 2) {
        mm_fwd<E_BF16, 64><<<dim3(3, gm2), 256, 0, stream>>>(GH1k, 1536, cw2t + lc * W2SZ,
            cb2 + lc * 384, nullptr, nullptr, nullptr, hn, nullptr, nullptr, nullptr,
            1536, 384, 0, 0.f, 0, 30, 0, 0, 0, 0, 0);
        bf16* t = hc; hc = hn; hn = t;
      } else {
        mm_fwd<E_F32ADD, 64><<<dim3(3, gm2), 256, 0, stream>>>(GH1k, 1536, cw2t + lc * W2SZ,
            cb2 + lc * 384, nullptr, outp, nullptr, nullptr, nullptr, nullptr, outp,
            1536, 384, 0, 0.f, 0, 30, 0, 0, 0, 0, 0);
      }
    }
  }
}